// Round 12
// baseline (982.385 us; speedup 1.0000x reference)
//
#include <hip/hip_runtime.h>

typedef long long LL;
typedef unsigned short ushort_t;
typedef __attribute__((ext_vector_type(8))) short bfrag;      // 8 bf16
typedef __attribute__((ext_vector_type(8))) _Float16 hfrag;   // 8 f16
typedef __attribute__((ext_vector_type(4))) float facc;
typedef __attribute__((ext_vector_type(4))) unsigned short us4;

// ---- problem constants ----
constexpr int CDIM  = 768;
constexpr int HEADS = 12;
constexpr int LT    = 64;
constexpr int NTOK  = 320;
constexpr int BATCH = 32;
constexpr int LKEEP = 180;
constexpr int LREM  = 76;
constexpr int NK    = 244;

// ---- d_out element offsets (all f32) ----
constexpr LL O_XRGB = 0;
constexpr LL O_XTIR = 5996544;
constexpr LL O_GIT  = 11993088;
constexpr LL O_GSN  = 11995136;
constexpr LL O_REM  = 12000896;
constexpr LL O_CR   = 12003328;
constexpr LL O_CT   = 51324928;
constexpr LL O_JS   = 90646528;

// ---- workspace float offsets ----
constexpr LL W_X1   = 0;          // Xh0/Xl0/Xh1/Xl1 (attn) -> X1c f32 compact (post-rank)
constexpr LL W_X1G  = 15728640;   // WPROJb | WFC1b(+294912) | WFC2b(+1474560)
constexpr LL W_XN   = 27746304;   // ATTb[0], ATTb[1] (2 x SZH ushort) -> XN2b (MLP)
constexpr LL W_QKV  = 35610624;   // Qh/Qm/Kh/Km (4 x SZH ushort) | H1b(batched)
constexpr LL W_ATT  = 59596800;   // Wh/Wl | Vt(+2000000) | part(+6000000) | srcmap(+6400000)

constexpr LL SZH = 7864320;

__device__ inline ushort_t cvt_bf16(float f) {
    union { float f; unsigned u; } x; x.f = f;
    unsigned u = x.u + 0x7fffu + ((x.u >> 16) & 1u);
    return (ushort_t)(u >> 16);
}
union h16u { _Float16 h; ushort_t u; };

#define GLL(gp, lp) __builtin_amdgcn_global_load_lds( \
    (const __attribute__((address_space(1))) unsigned int*)(gp), \
    (__attribute__((address_space(3))) unsigned int*)(lp), 16, 0, 0)

// bijective XCD-chunked decode (m204): same-by blocks land on one XCD
__device__ inline void xcd_decode(int& bx, int& by) {
    int gx = gridDim.x;
    int nwg = gx * gridDim.y;
    int bid = blockIdx.y * gx + blockIdx.x;
    int q = nwg >> 3, r = nwg & 7;
    int xcd = bid & 7, i = bid >> 3;
    int wg = (xcd < r ? xcd * (q + 1) : r * (q + 1) + (xcd - r) * q) + i;
    bx = wg % gx;
    by = wg / gx;
}

// =======================================================================
// merged weight prep: w_proj->bf16, w_qkv->f16 hi/lo, w_fc1/2->bf16
// =======================================================================
__global__ __launch_bounds__(256)
void prep_weights(const float* __restrict__ wproj, const float* __restrict__ wqkv,
                  const float* __restrict__ wfc1, const float* __restrict__ wfc2,
                  ushort_t* __restrict__ WPROJb, ushort_t* __restrict__ Wh,
                  ushort_t* __restrict__ Wl, ushort_t* __restrict__ WFC1b,
                  ushort_t* __restrict__ WFC2b)
{
    int i = blockIdx.x * 256 + threadIdx.x;
    if (i < 147456) {
        int j = i * 4;
        float4 v = *(const float4*)(wproj + j);
        us4 o;
        o[0] = cvt_bf16(v.x); o[1] = cvt_bf16(v.y);
        o[2] = cvt_bf16(v.z); o[3] = cvt_bf16(v.w);
        *(us4*)(WPROJb + j) = o;
    } else if (i < 589824) {
        int j = (i - 147456) * 4;
        float4 v = *(const float4*)(wqkv + j);
        us4 h, l;
        #pragma unroll
        for (int k = 0; k < 4; ++k) {
            float f = (k == 0 ? v.x : k == 1 ? v.y : k == 2 ? v.z : v.w);
            h16u hh, ll;
            hh.h = (_Float16)f;
            ll.h = (_Float16)(f - (float)hh.h);
            h[k] = hh.u; l[k] = ll.u;
        }
        *(us4*)(Wh + j) = h;
        *(us4*)(Wl + j) = l;
    } else if (i < 1179648) {
        int j = (i - 589824) * 4;
        float4 v = *(const float4*)(wfc1 + j);
        us4 o;
        o[0] = cvt_bf16(v.x); o[1] = cvt_bf16(v.y);
        o[2] = cvt_bf16(v.z); o[3] = cvt_bf16(v.w);
        *(us4*)(WFC1b + j) = o;
    } else {
        int j = (i - 1179648) * 4;
        float4 v = *(const float4*)(wfc2 + j);
        us4 o;
        o[0] = cvt_bf16(v.x); o[1] = cvt_bf16(v.y);
        o[2] = cvt_bf16(v.z); o[3] = cvt_bf16(v.w);
        *(us4*)(WFC2b + j) = o;
    }
}

// =======================================================================
// LayerNorm -> bf16 (direct rows, MLP stage)
// =======================================================================
template<bool B16OUT>
__global__ __launch_bounds__(256)
void ln_kernel(const float* __restrict__ x, const float* __restrict__ g,
               const float* __restrict__ bta, void* __restrict__ y)
{
    LL row = blockIdx.x;
    const float* xr = x + row * 768;
    int t = threadIdx.x;
    float v0 = xr[t], v1 = xr[t + 256], v2 = xr[t + 512];
    __shared__ float red[256];
    red[t] = v0 + v1 + v2;
    __syncthreads();
    for (int s = 128; s; s >>= 1) { if (t < s) red[t] += red[t + s]; __syncthreads(); }
    float mean = red[0] / 768.0f;
    __syncthreads();
    float d0 = v0 - mean, d1 = v1 - mean, d2 = v2 - mean;
    red[t] = d0 * d0 + d1 * d1 + d2 * d2;
    __syncthreads();
    for (int s = 128; s; s >>= 1) { if (t < s) red[t] += red[t + s]; __syncthreads(); }
    float var = red[0] / 768.0f;
    float rs = 1.0f / sqrtf(var + 1e-5f);
    float o0 = d0 * rs * g[t]       + bta[t];
    float o1 = d1 * rs * g[t + 256] + bta[t + 256];
    float o2 = d2 * rs * g[t + 512] + bta[t + 512];
    if (B16OUT) {
        ushort_t* yr = (ushort_t*)y + row * 768;
        yr[t] = cvt_bf16(o0); yr[t + 256] = cvt_bf16(o1); yr[t + 512] = cvt_bf16(o2);
    } else {
        float* yr = (float*)y + row * 768;
        yr[t] = o0; yr[t + 256] = o1; yr[t + 512] = o2;
    }
}

// =======================================================================
// LayerNorm -> f16 hi/lo split, BOTH modalities in one launch
// =======================================================================
__global__ __launch_bounds__(256)
void ln_f16x2(const float* __restrict__ x0, const float* __restrict__ x1,
              const float* __restrict__ g, const float* __restrict__ bta,
              ushort_t* __restrict__ ybase)
{
    int row = blockIdx.x;
    int mod = row >= 10240;
    int lrow = row - mod * 10240;
    const float* xr = (mod ? x1 : x0) + (LL)lrow * 768;
    ushort_t* yh = ybase + (LL)mod * 2 * SZH + (LL)lrow * 768;
    ushort_t* yl = yh + SZH;
    int t = threadIdx.x;
    float v0 = xr[t], v1 = xr[t + 256], v2 = xr[t + 512];
    __shared__ float red[256];
    red[t] = v0 + v1 + v2;
    __syncthreads();
    for (int s = 128; s; s >>= 1) { if (t < s) red[t] += red[t + s]; __syncthreads(); }
    float mean = red[0] / 768.0f;
    __syncthreads();
    float d0 = v0 - mean, d1 = v1 - mean, d2 = v2 - mean;
    red[t] = d0 * d0 + d1 * d1 + d2 * d2;
    __syncthreads();
    for (int s = 128; s; s >>= 1) { if (t < s) red[t] += red[t + s]; __syncthreads(); }
    float var = red[0] / 768.0f;
    float rs = 1.0f / sqrtf(var + 1e-5f);
    #pragma unroll
    for (int c = 0; c < 3; ++c) {
        float d = (c == 0 ? d0 : c == 1 ? d1 : d2);
        int idx = t + c * 256;
        float o = d * rs * g[idx] + bta[idx];
        h16u hi, lo;
        hi.h = (_Float16)o;
        lo.h = (_Float16)(o - (float)hi.h);
        yh[idx] = hi.u;
        yl[idx] = lo.u;
    }
}

// =======================================================================
// QKV GEMM (VERBATIM from passing round 11)
// =======================================================================
__global__ __launch_bounds__(256)
void gemm_qkv(const ushort_t* __restrict__ Ah, const ushort_t* __restrict__ Al,
              const ushort_t* __restrict__ Bh, const ushort_t* __restrict__ Bl,
              ushort_t* __restrict__ Q1, ushort_t* __restrict__ Q2,
              ushort_t* __restrict__ K1, ushort_t* __restrict__ K2,
              ushort_t* __restrict__ Vt)
{
    __shared__ ushort_t Ahs[8192], Als[8192], Bhs[8192], Bls[8192];
    int bx, by;
    xcd_decode(bx, by);
    const int t = threadIdx.x;
    const int wave = t >> 6, lane = t & 63;
    const int wr = wave >> 1, wc = wave & 1;
    const int lr = lane & 15, lh = lane >> 4;
    const LL bm = (LL)by * 128, bn = (LL)bx * 128;
    const bool vt = (bx >= 12);

    facc acc[4][4];
    #pragma unroll
    for (int i = 0; i < 4; ++i)
        #pragma unroll
        for (int j = 0; j < 4; ++j) acc[i][j] = (facc)(0.0f);

    const LL soff = (bm + wave * 16 + (lane >> 2)) * (LL)768 + (lane & 3) * 8;
    const LL boff = (bn + wave * 16 + (lane >> 2)) * (LL)768 + (lane & 3) * 8;
    const LL a64 = (LL)64 * 768;

    GLL(Ah + soff,       &Ahs[wave * 512]);
    GLL(Ah + soff + a64, &Ahs[2048 + wave * 512]);
    GLL(Bh + boff,       &Bhs[wave * 512]);
    GLL(Bh + boff + a64, &Bhs[2048 + wave * 512]);
    if (!vt) {
        GLL(Al + soff,       &Als[wave * 512]);
        GLL(Al + soff + a64, &Als[2048 + wave * 512]);
        GLL(Bl + boff,       &Bls[wave * 512]);
        GLL(Bl + boff + a64, &Bls[2048 + wave * 512]);
    }
    __syncthreads();

    int cur = 0;
    for (int k0 = 0; k0 < 768; k0 += 32) {
        int nb = (cur ^ 1) * 4096;
        if (k0 + 32 < 768) {
            GLL(Ah + soff + k0 + 32,       &Ahs[nb + wave * 512]);
            GLL(Ah + soff + k0 + 32 + a64, &Ahs[nb + 2048 + wave * 512]);
            GLL(Bh + boff + k0 + 32,       &Bhs[nb + wave * 512]);
            GLL(Bh + boff + k0 + 32 + a64, &Bhs[nb + 2048 + wave * 512]);
            if (!vt) {
                GLL(Al + soff + k0 + 32,       &Als[nb + wave * 512]);
                GLL(Al + soff + k0 + 32 + a64, &Als[nb + 2048 + wave * 512]);
                GLL(Bl + boff + k0 + 32,       &Bls[nb + wave * 512]);
                GLL(Bl + boff + k0 + 32 + a64, &Bls[nb + 2048 + wave * 512]);
            }
        }
        int cb = cur * 4096;
        hfrag ah[4], bh[4];
        #pragma unroll
        for (int mi = 0; mi < 4; ++mi)
            ah[mi] = *(const hfrag*)&Ahs[cb + (wr * 64 + mi * 16 + lr) * 32 + lh * 8];
        #pragma unroll
        for (int ni = 0; ni < 4; ++ni)
            bh[ni] = *(const hfrag*)&Bhs[cb + (wc * 64 + ni * 16 + lr) * 32 + lh * 8];
        if (!vt) {
            hfrag al[4], bl[4];
            #pragma unroll
            for (int mi = 0; mi < 4; ++mi)
                al[mi] = *(const hfrag*)&Als[cb + (wr * 64 + mi * 16 + lr) * 32 + lh * 8];
            #pragma unroll
            for (int ni = 0; ni < 4; ++ni)
                bl[ni] = *(const hfrag*)&Bls[cb + (wc * 64 + ni * 16 + lr) * 32 + lh * 8];
            #pragma unroll
            for (int mi = 0; mi < 4; ++mi)
                #pragma unroll
                for (int ni = 0; ni < 4; ++ni) {
                    acc[mi][ni] = __builtin_amdgcn_mfma_f32_16x16x32_f16(al[mi], bh[ni], acc[mi][ni], 0, 0, 0);
                    acc[mi][ni] = __builtin_amdgcn_mfma_f32_16x16x32_f16(ah[mi], bl[ni], acc[mi][ni], 0, 0, 0);
                    acc[mi][ni] = __builtin_amdgcn_mfma_f32_16x16x32_f16(ah[mi], bh[ni], acc[mi][ni], 0, 0, 0);
                }
        } else {
            #pragma unroll
            for (int mi = 0; mi < 4; ++mi)
                #pragma unroll
                for (int ni = 0; ni < 4; ++ni)
                    acc[mi][ni] = __builtin_amdgcn_mfma_f32_16x16x32_f16(ah[mi], bh[ni], acc[mi][ni], 0, 0, 0);
        }
        __syncthreads();
        cur ^= 1;
    }

    #pragma unroll
    for (int mi = 0; mi < 4; ++mi)
        #pragma unroll
        for (int ni = 0; ni < 4; ++ni)
            #pragma unroll
            for (int j = 0; j < 4; ++j) {
                int r = (int)bm + wr * 64 + mi * 16 + lh * 4 + j;
                int c = (int)bn + wc * 64 + ni * 16 + lr;
                int b = r / 320, tt = r - b * 320;
                int s = c / 768, rem = c - s * 768;
                int h = rem >> 6, d = rem & 63;
                LL hb = (LL)(b * 12 + h) * 20480;
                float v = acc[mi][ni][j];
                if (s == 2) {
                    Vt[hb + d * 320 + tt] = cvt_bf16(v);
                } else {
                    h16u a1, a2;
                    a1.h = (_Float16)v;
                    a2.h = (_Float16)(v - (float)a1.h);
                    LL idx = hb + (LL)tt * 64 + d;
                    if (s == 0) { Q1[idx] = a1.u; Q2[idx] = a2.u; }
                    else        { K1[idx] = a1.u; K2[idx] = a2.u; }
                }
            }
}

// =======================================================================
// Fused attention (VERBATIM from passing rounds 8/10/11)
// =======================================================================
__global__ __launch_bounds__(256, 2)
void fused_attn(const ushort_t* __restrict__ Qh, const ushort_t* __restrict__ Qm,
                const ushort_t* __restrict__ Kh, const ushort_t* __restrict__ Km,
                const ushort_t* __restrict__ Vt,
                float* __restrict__ corr, ushort_t* __restrict__ attb,
                double* __restrict__ part, int mod)
{
    __shared__ __align__(128) unsigned char lds[81920];
    constexpr int PS = 40960;

    const int t = threadIdx.x;
    const int wave = t >> 6, lane = t & 63;
    const int lr = lane & 15, lh = lane >> 4;
    const int id  = blockIdx.x;
    const int xcd = id & 7;
    const int rem = id >> 3;
    const int grp = rem / 5;
    const int r0i = rem - grp * 5;
    const int bh  = grp * 8 + xcd;
    const int b = bh / 12, h = bh - b * 12;
    const int r0 = r0i * 64;
    const LL kvbase = (LL)bh * 20480;

    const LL qoff = kvbase + (LL)(r0 + wave * 16 + lr) * 64 + lh * 8;
    hfrag qh0 = *(const hfrag*)(Qh + qoff), qh1 = *(const hfrag*)(Qh + qoff + 32);
    hfrag qm0 = *(const hfrag*)(Qm + qoff), qm1 = *(const hfrag*)(Qm + qoff + 32);

    facc sacc[20];
    #pragma unroll
    for (int ct = 0; ct < 20; ++ct) sacc[ct] = (facc)(0.0f);

    #pragma unroll
    for (int ha = 0; ha < 5; ++ha) {
        if (ha) __syncthreads();
        #pragma unroll
        for (int i = 0; i < 4; ++i) {
            int id2 = wave * 4 + i;
            int s = id2 >> 3, c = id2 & 7;
            int local = c * 1024 + lane * 16;
            int row = local >> 7;
            int sb = local ^ ((row & 7) << 4);
            LL src = kvbase + (LL)ha * 4096 + (sb >> 1);
            const ushort_t* kp = (s == 0) ? Kh : Km;
            GLL(kp + src, &lds[s * 8192 + c * 1024]);
        }
        __syncthreads();

        #pragma unroll
        for (int ctl = 0; ctl < 4; ++ctl) {
            int tokl = ctl * 16 + lr;
            int x = (tokl & 7) << 4;
            const unsigned char* kb = lds + tokl * 128;
            int o0 = (lh * 16) ^ x;
            int o1 = (64 + lh * 16) ^ x;
            hfrag kh0 = *(const hfrag*)(kb + o0);
            hfrag kh1 = *(const hfrag*)(kb + o1);
            hfrag km0 = *(const hfrag*)(kb + 8192 + o0);
            hfrag km1 = *(const hfrag*)(kb + 8192 + o1);
            facc a = sacc[ha * 4 + ctl];
            a = __builtin_amdgcn_mfma_f32_16x16x32_f16(qm0, kh0, a, 0, 0, 0);
            a = __builtin_amdgcn_mfma_f32_16x16x32_f16(qh0, km0, a, 0, 0, 0);
            a = __builtin_amdgcn_mfma_f32_16x16x32_f16(qh0, kh0, a, 0, 0, 0);
            a = __builtin_amdgcn_mfma_f32_16x16x32_f16(qm1, kh1, a, 0, 0, 0);
            a = __builtin_amdgcn_mfma_f32_16x16x32_f16(qh1, km1, a, 0, 0, 0);
            a = __builtin_amdgcn_mfma_f32_16x16x32_f16(qh1, kh1, a, 0, 0, 0);
            sacc[ha * 4 + ctl] = a;
        }
    }

    __syncthreads();

    #pragma unroll
    for (int i = 0; i < 10; ++i) {
        int chunk = wave * 10 + i;
        int gs = chunk * 1024 + lane * 16;
        int d = gs / 640;
        int w = gs - d * 640;
        int sb = d * 640 + (w ^ ((d & 7) << 4));
        GLL(Vt + kvbase + (sb >> 1), &lds[chunk * 1024]);
    }

    float rs4[4];
    #pragma unroll
    for (int j = 0; j < 4; ++j) {
        float m = sacc[0][j];
        #pragma unroll
        for (int ct = 1; ct < 20; ++ct) m = fmaxf(m, sacc[ct][j]);
        #pragma unroll
        for (int o = 1; o < 16; o <<= 1) m = fmaxf(m, __shfl_xor(m, o, 64));
        m *= 0.125f;
        float s = 0.0f;
        #pragma unroll
        for (int ct = 0; ct < 20; ++ct) {
            float e = expf(sacc[ct][j] * 0.125f - m);
            sacc[ct][j] = e;
            s += e;
        }
        #pragma unroll
        for (int o = 1; o < 16; o <<= 1) s += __shfl_xor(s, o, 64);
        float rs = 1.0f / s;
        rs4[j] = rs;

        int prow = wave * 16 + lh * 4 + j;
        int xr = (prow & 7) << 4;
        #pragma unroll
        for (int ct = 0; ct < 20; ++ct) {
            int pcol = ct * 16 + lr;
            *(ushort_t*)(lds + PS + prow * 640 + ((pcol * 2) ^ xr)) =
                cvt_bf16(sacc[ct][j] * rs);
        }
    }

    __syncthreads();

    facc oacc[4];
    #pragma unroll
    for (int dt = 0; dt < 4; ++dt) oacc[dt] = (facc)(0.0f);
    int prow2 = wave * 16 + lr;
    int xp = (prow2 & 7) << 4;
    #pragma unroll
    for (int k0 = 0; k0 < 10; ++k0) {
        bfrag pa = *(const bfrag*)(lds + PS + prow2 * 640 + ((k0 * 64 + lh * 16) ^ xp));
        #pragma unroll
        for (int dt = 0; dt < 4; ++dt) {
            int dcol = dt * 16 + lr;
            bfrag vb = *(const bfrag*)(lds + dcol * 640 + ((k0 * 64 + lh * 16) ^ ((dcol & 7) << 4)));
            oacc[dt] = __builtin_amdgcn_mfma_f32_16x16x32_bf16(pa, vb, oacc[dt], 0, 0, 0);
        }
    }
    #pragma unroll
    for (int dt = 0; dt < 4; ++dt)
        #pragma unroll
        for (int j = 0; j < 4; ++j) {
            int grow = r0 + wave * 16 + lh * 4 + j;
            int gcol = h * 64 + dt * 16 + lr;
            attb[(LL)(b * 320 + grow) * 768 + gcol] = cvt_bf16(oacc[dt][j]);
        }

    __syncthreads();

    #pragma unroll
    for (int ct = 0; ct < 20; ++ct) {
        int pcol = ct * 16 + lr;
        #pragma unroll
        for (int j = 0; j < 4; ++j) {
            int prow = wave * 16 + lh * 4 + j;
            *(float*)(lds + (prow * 320 + pcol) * 4) = sacc[ct][j] * rs4[j];
        }
    }
    __syncthreads();

    float* crow = corr + (LL)bh * 102400 + (LL)r0 * 320;
    #pragma unroll
    for (int i = 0; i < 20; ++i) {
        int idx = i * 256 + t;
        int row = idx / 80, c4 = idx - row * 80;
        float4 v = *(const float4*)(lds + (row * 320 + c4 * 4) * 4);
        *(float4*)(crow + row * 320 + c4 * 4) = v;
    }

    if (r0i == 0) {
        double s64 = 0.0;
        for (int r = 0; r < 64; ++r)
            s64 += (double)*(const float*)(lds + (r * 320 + 64 + t) * 4);
        part[((LL)mod * 384 + bh) * 256 + t] = s64;
    }
}

// =======================================================================
// bf16 MFMA GEMM 16x16x32 128^2 (proj / fc2) — VERBATIM from round 11
// =======================================================================
template<int EPI>
__global__ __launch_bounds__(256)
void gemm_mfma(const ushort_t* __restrict__ A, const ushort_t* __restrict__ B,
               void* __restrict__ Cv, const float* __restrict__ bias,
               const float* __restrict__ res, const int* __restrict__ amap,
               int K, int lda, int ldb, int ldc, int ldres)
{
    __shared__ ushort_t As[8192];
    __shared__ ushort_t Bs[8192];
    int bx, by;
    xcd_decode(bx, by);
    const int t = threadIdx.x;
    const int wave = t >> 6, lane = t & 63;
    const int wr = wave >> 1, wc = wave & 1;
    const LL bm = (LL)by * 128, bn = (LL)bx * 128;

    facc acc[4][4];
    #pragma unroll
    for (int i = 0; i < 4; ++i)
        #pragma unroll
        for (int j = 0; j < 4; ++j) acc[i][j] = (facc)(0.0f);

    const int lr = lane & 15, lh = lane >> 4;
    int r1 = (int)bm + wave * 16 + (lane >> 2);
    int r2 = r1 + 64;
    if (amap) { r1 = amap[r1]; r2 = amap[r2]; }
    const ushort_t* gA1 = A + (LL)r1 * lda + (lane & 3) * 8;
    const ushort_t* gA2 = A + (LL)r2 * lda + (lane & 3) * 8;
    const ushort_t* gB = B + (bn + wave * 16 + (lane >> 2)) * ldb + (lane & 3) * 8;
    const LL b64 = (LL)64 * ldb;

    GLL(gA1,       &As[wave * 512]);
    GLL(gA2,       &As[2048 + wave * 512]);
    GLL(gB,        &Bs[wave * 512]);
    GLL(gB + b64,  &Bs[2048 + wave * 512]);
    __syncthreads();

    int cur = 0;
    for (int k0 = 0; k0 < K; k0 += 32) {
        int nb = (cur ^ 1) * 4096;
        if (k0 + 32 < K) {
            GLL(gA1 + k0 + 32,       &As[nb + wave * 512]);
            GLL(gA2 + k0 + 32,       &As[nb + 2048 + wave * 512]);
            GLL(gB + k0 + 32,        &Bs[nb + wave * 512]);
            GLL(gB + k0 + 32 + b64,  &Bs[nb + 2048 + wave * 512]);
        }
        int cb = cur * 4096;
        bfrag a[4], b[4];
        #pragma unroll
        for (int m = 0; m < 4; ++m)
            a[m] = *(const bfrag*)&As[cb + (wr * 64 + m * 16 + lr) * 32 + lh * 8];
        #pragma unroll
        for (int n = 0; n < 4; ++n)
            b[n] = *(const bfrag*)&Bs[cb + (wc * 64 + n * 16 + lr) * 32 + lh * 8];
        #pragma unroll
        for (int m = 0; m < 4; ++m)
            #pragma unroll
            for (int n = 0; n < 4; ++n)
                acc[m][n] = __builtin_amdgcn_mfma_f32_16x16x32_bf16(a[m], b[n], acc[m][n], 0, 0, 0);
        __syncthreads();
        cur ^= 1;
    }

    #pragma unroll
    for (int m = 0; m < 4; ++m) {
        #pragma unroll
        for (int n = 0; n < 4; ++n) {
            #pragma unroll
            for (int j = 0; j < 4; ++j) {
                LL r = bm + wr * 64 + m * 16 + lh * 4 + j;
                LL c = bn + wc * 64 + n * 16 + lr;
                float v = acc[m][n][j] + bias[c];
                if (EPI == 1) {
                    v = 0.5f * v * (erff(v * 0.70710678118654752f) + 1.0f);
                    ((ushort_t*)Cv)[r * ldc + c] = cvt_bf16(v);
                } else {
                    LL rr = amap ? (LL)amap[r] : r;
                    v += res[rr * ldres + c];
                    ((float*)Cv)[r * ldc + c] = v;
                }
            }
        }
    }
}

// =======================================================================
// NEW: 256^2-tile bf16 GEMM for fc1. BK=32, 8 waves, 4 LDS kt-buffers,
// depth-3 counted vmcnt (T3/T4), st_16x32 swizzle (T2, both-sides via
// inverse-swizzled global source, rule #21), setprio around MFMA (T5).
// K=768 fixed (24 kt). Epilogue: bias+GELU -> bf16, ldc=3072.
// =======================================================================
__global__ __launch_bounds__(512, 1)
void gemm256_fc1(const ushort_t* __restrict__ A, const ushort_t* __restrict__ B,
                 ushort_t* __restrict__ C, const float* __restrict__ bias)
{
    __shared__ ushort_t As[32768];   // 4 bufs x 16KB ([16 rg][16 r][32 c] swz)
    __shared__ ushort_t Bs[32768];
    int bx, by;
    xcd_decode(bx, by);
    const int tid = threadIdx.x;
    const int wid = tid >> 6, lane = tid & 63;
    const int wr = wid >> 2, wc = wid & 3;          // 2M x 4N waves
    const int lr = lane & 15, lh = lane >> 4;
    const LL bm = (LL)by * 256, bn = (LL)bx * 256;

    facc acc[8][4];
    #pragma unroll
    for (int m = 0; m < 8; ++m)
        #pragma unroll
        for (int n = 0; n < 4; ++n) acc[m][n] = (facc)(0.0f);

    // per-thread staging: 2 GLL per operand per kt; linear LDS dest,
    // inverse-swizzled global source (involution: XOR bit5 by bit9)
    int srow[2], sk[2];
    #pragma unroll
    for (int l = 0; l < 2; ++l) {
        int o = l * 8192 + tid * 16;
        int rg = o >> 10;
        int o10 = o & 1023;
        int op = o10 ^ (((o10 >> 9) & 1) << 5);
        srow[l] = rg * 16 + (op >> 6);
        sk[l]   = (op & 63) >> 1;
    }

    #define STAGE256(kt) { \
        int _bo = ((kt) & 3) * 8192; \
        _Pragma("unroll") \
        for (int l = 0; l < 2; ++l) { \
            GLL(A + (bm + srow[l]) * (LL)768 + (kt) * 32 + sk[l], \
                &As[_bo + l * 4096 + tid * 8]); \
            GLL(B + (bn + srow[l]) * (LL)768 + (kt) * 32 + sk[l], \
                &Bs[_bo + l * 4096 + tid * 8]); \
        } }

    // prologue: stage kt 0,1,2; wait kt0 (outstanding <= 8 = kt1,kt2)
    STAGE256(0); STAGE256(1); STAGE256(2);
    asm volatile("s_waitcnt vmcnt(8)" ::: "memory");
    __builtin_amdgcn_sched_barrier(0);
    __builtin_amdgcn_s_barrier();

    const int b10 = lr * 64 + lh * 16;
    const int sb = (b10 ^ (((lr >> 3) & 1) << 5)) >> 1;   // ushort offset

    for (int kt = 0; kt < 24; ++kt) {
        int cb = (kt & 3) * 8192;
        bfrag a[4], b[4];
        // ---- phase A: reads for m0..3 + all B; stage kt+3 ----
        #pragma unroll
        for (int m = 0; m < 4; ++m)
            a[m] = *(const bfrag*)&As[cb + ((wr * 8 + m) << 9) + sb];
        #pragma unroll
        for (int n = 0; n < 4; ++n)
            b[n] = *(const bfrag*)&Bs[cb + ((wc * 4 + n) << 9) + sb];
        if (kt + 3 < 24) STAGE256(kt + 3);
        __builtin_amdgcn_s_setprio(1);
        #pragma unroll
        for (int m = 0; m < 4; ++m)
            #pragma unroll
            for (int n = 0; n < 4; ++n)
                acc[m][n] = __builtin_amdgcn_mfma_f32_16x16x32_bf16(a[m], b[n], acc[m][n], 0, 0, 0);
        __builtin_amdgcn_s_setprio(0);
        // ---- phase B: reads m4..7, B reused ----
        #pragma unroll
        for (int m = 0; m < 4; ++m)
            a[m] = *(const bfrag*)&As[cb + ((wr * 8 + 4 + m) << 9) + sb];
        __builtin_amdgcn_s_setprio(1);
        #pragma unroll
        for (int m = 0; m < 4; ++m)
            #pragma unroll
            for (int n = 0; n < 4; ++n)
                acc[4 + m][n] = __builtin_amdgcn_mfma_f32_16x16x32_bf16(a[m], b[n], acc[4 + m][n], 0, 0, 0);
        __builtin_amdgcn_s_setprio(0);
        // ---- boundary: counted wait for kt+1, publish ----
        if (kt < 23) {
            if (kt < 21)      asm volatile("s_waitcnt vmcnt(8)" ::: "memory");
            else if (kt == 21) asm volatile("s_waitcnt vmcnt(4)" ::: "memory");
            else               asm volatile("s_waitcnt vmcnt(0)" ::: "memory");
            __builtin_amdgcn_sched_barrier(0);
            __builtin_amdgcn_s_barrier();
        }
    }
    #undef STAGE256

    #pragma unroll
    for (int m = 0; m < 8; ++m)
        #pragma unroll
        for (int n = 0; n < 4; ++n)
            #pragma unroll
            for (int j = 0; j < 4; ++j) {
                LL r = bm + wr * 128 + m * 16 + lh * 4 + j;
                LL c = bn + wc * 64 + n * 16 + lr;
                float v = acc[m][n][j] + bias[c];
                v = 0.5f * v * (erff(v * 0.70710678118654752f) + 1.0f);
                C[r * 3072 + c] = cvt_bf16(v);
            }
}

// =======================================================================
// rank_all: f64 score combine + stable rank + srcmap + git/js copies
// =======================================================================
__global__ __launch_bounds__(256)
void rank_all(const double* __restrict__ part, const int* __restrict__ gis,
              const int* __restrict__ git, const float* __restrict__ js,
              int* __restrict__ srcmap, float* __restrict__ out)
{
    int b = blockIdx.x, j = threadIdx.x;
    double acc = 0.0;
    for (int h = 0; h < 12; ++h) {
        LL i0 = ((LL)(b * 12 + h)) * 256 + j;
        acc += (part[i0] + part[98304 + i0]) / 64.0;
    }
    double sj = acc / 12.0;
    __shared__ double s[256];
    __shared__ int sord[256];
    s[j] = sj;
    __syncthreads();
    int r = 0;
    for (int i = 0; i < 256; ++i) {
        double si = s[i];
        r += (si > sj) || (si == sj && i < j);
    }
    sord[r] = j;
    float gv = (float)gis[b * 256 + j];
    if (r < LKEEP) out[O_GSN + b * LKEEP + r] = gv;
    else           out[O_REM + b * LREM + (r - LKEEP)] = gv;
    __syncthreads();
    if (j < NK) {
        int src = (j < LT) ? j : (LT + sord[j - LT]);
        srcmap[b * NK + j] = b * NTOK + src;
    }
    if (j < 64) out[O_GIT + b * 64 + j] = (float)git[b * 64 + j];
    if (b == 0 && j == 0) out[O_JS] = js[0];
}

// =======================================================================
extern "C" void kernel_launch(void* const* d_in, const int* in_sizes, int n_in,
                              void* d_out, int out_size, void* d_ws, size_t ws_size,
                              hipStream_t stream)
{
    const float* xin_m[2] = { (const float*)d_in[0], (const float*)d_in[1] };
    const int*   git    = (const int*)d_in[2];
    const int*   gis    = (const int*)d_in[3];
    const float* js     = (const float*)d_in[7];
    const float* g1     = (const float*)d_in[8];
    const float* b1     = (const float*)d_in[9];
    const float* w_qkv  = (const float*)d_in[10];
    const float* w_proj = (const float*)d_in[11];
    const float* b_proj = (const float*)d_in[12];
    const float* g2     = (const float*)d_in[13];
    const float* b2     = (const float*)d_in[14];
    const float* w_fc1  = (const float*)d_in[15];
    const float* b_fc1  = (const float*)d_in[16];
    const float* w_fc2  = (const float*)d_in[17];
    const float* b_fc2  = (const float*)d_in[18];

    float* out = (float*)d_out;
    float* ws  = (float*)d_ws;

    // overlays
    ushort_t* Xbase = (ushort_t*)(ws + W_X1);          // Xh0/Xl0/Xh1/Xl1
    float*    X1c  = ws + W_X1;                        // post-rank (X dead)
    ushort_t* ATTb0 = (ushort_t*)(ws + W_XN);
    ushort_t* ATTb1 = ATTb0 + SZH;
    ushort_t* QK  = (ushort_t*)(ws + W_QKV);
    ushort_t* Qh2 = QK,           *Qm2 = QK + SZH;
    ushort_t* Kh2 = QK + 2 * SZH, *Km2 = QK + 3 * SZH;
    ushort_t* Wh  = (ushort_t*)(ws + W_ATT);
    ushort_t* Wl  = Wh + 1769472;
    ushort_t* Vt  = (ushort_t*)(ws + W_ATT + 2000000);
    double*   part = (double*)(ws + W_ATT + 6000000);
    int*      srcmap = (int*)(ws + W_ATT + 6400000);
    ushort_t* WPROJb = (ushort_t*)(ws + W_X1G);
    ushort_t* WFC1b  = (ushort_t*)(ws + W_X1G + 294912);
    ushort_t* WFC2b  = (ushort_t*)(ws + W_X1G + 1474560);
    ushort_t* XN2b   = (ushort_t*)(ws + W_XN);
    ushort_t* H1b    = (ushort_t*)(ws + W_QKV);

    prep_weights<<<dim3(6912), dim3(256), 0, stream>>>(
        w_proj, w_qkv, w_fc1, w_fc2, WPROJb, Wh, Wl, WFC1b, WFC2b);

    ln_f16x2<<<dim3(2 * BATCH * NTOK), dim3(256), 0, stream>>>(
        xin_m[0], xin_m[1], g1, b1, Xbase);

    for (int m = 0; m < 2; ++m) {
        float* corr = out + (m ? O_CT : O_CR);
        ushort_t* ATTbm = m ? ATTb1 : ATTb0;
        ushort_t* Xh = Xbase + (LL)m * 2 * SZH;
        ushort_t* Xl = Xh + SZH;

        gemm_qkv<<<dim3(18, 80), dim3(256), 0, stream>>>(
            Xh, Xl, Wh, Wl, Qh2, Qm2, Kh2, Km2, Vt);

        fused_attn<<<dim3(1920), dim3(256), 0, stream>>>(
            Qh2, Qm2, Kh2, Km2, Vt, corr, ATTbm, part, m);
    }

    rank_all<<<dim3(BATCH), dim3(256), 0, stream>>>(part, gis, git, js, srcmap, out);

    for (int m = 0; m < 2; ++m) {
        gemm_mfma<2><<<dim3(6, 61), dim3(256), 0, stream>>>(
            m ? ATTb1 : ATTb0, WPROJb, X1c + (LL)m * 5996544, b_proj,
            xin_m[m], srcmap, 768, 768, 768, 768, 768);
    }

    ln_kernel<true><<<dim3(2 * BATCH * NK), dim3(256), 0, stream>>>(
        X1c, g2, b2, XN2b);

    // fc1 on the new 256^2 deep-pipelined kernel (M=15616, N=3072, K=768)
    gemm256_fc1<<<dim3(12, 61), dim3(512), 0, stream>>>(XN2b, WFC1b, H1b, b_fc1);

    gemm_mfma<2><<<dim3(6, 122), dim3(256), 0, stream>>>(
        H1b, WFC2b, out + O_XRGB, b_fc2, X1c, nullptr, 3072, 3072, 3072, 768, 768);
}

// Round 13
// 878.857 us; speedup vs baseline: 1.1178x; 1.1178x over previous
//
#include <hip/hip_runtime.h>

typedef long long LL;
typedef unsigned short ushort_t;
typedef __attribute__((ext_vector_type(8))) short bfrag;      // 8 bf16
typedef __attribute__((ext_vector_type(8))) _Float16 hfrag;   // 8 f16
typedef __attribute__((ext_vector_type(4))) float facc;
typedef __attribute__((ext_vector_type(4))) unsigned short us4;

// ---- problem constants ----
constexpr int CDIM  = 768;
constexpr int HEADS = 12;
constexpr int LT    = 64;
constexpr int NTOK  = 320;
constexpr int BATCH = 32;
constexpr int LKEEP = 180;
constexpr int LREM  = 76;
constexpr int NK    = 244;

// ---- d_out element offsets (all f32) ----
constexpr LL O_XRGB = 0;
constexpr LL O_XTIR = 5996544;
constexpr LL O_GIT  = 11993088;
constexpr LL O_GSN  = 11995136;
constexpr LL O_REM  = 12000896;
constexpr LL O_CR   = 12003328;
constexpr LL O_CT   = 51324928;
constexpr LL O_JS   = 90646528;

// ---- workspace float offsets ----
constexpr LL W_X1   = 0;          // Xh0/Xl0/Xh1/Xl1 (attn) -> X1c f32 compact (post-rank)
constexpr LL W_X1G  = 15728640;   // WPROJb | WFC1b(+294912) | WFC2b(+1474560)
constexpr LL W_XN   = 27746304;   // ATTb[0], ATTb[1] (2 x SZH ushort) -> XN2b (MLP)
constexpr LL W_QKV  = 35610624;   // Qh/Qm/Kh/Km (4 x SZH ushort) | H1b(batched)
constexpr LL W_ATT  = 59596800;   // Wh/Wl | Vt(+2000000) | part(+6000000) | srcmap(+6400000)

constexpr LL SZH = 7864320;

__device__ inline ushort_t cvt_bf16(float f) {
    union { float f; unsigned u; } x; x.f = f;
    unsigned u = x.u + 0x7fffu + ((x.u >> 16) & 1u);
    return (ushort_t)(u >> 16);
}
union h16u { _Float16 h; ushort_t u; };

#define GLL(gp, lp) __builtin_amdgcn_global_load_lds( \
    (const __attribute__((address_space(1))) unsigned int*)(gp), \
    (__attribute__((address_space(3))) unsigned int*)(lp), 16, 0, 0)

// bijective XCD-chunked decode (m204): same-by blocks land on one XCD
__device__ inline void xcd_decode(int& bx, int& by) {
    int gx = gridDim.x;
    int nwg = gx * gridDim.y;
    int bid = blockIdx.y * gx + blockIdx.x;
    int q = nwg >> 3, r = nwg & 7;
    int xcd = bid & 7, i = bid >> 3;
    int wg = (xcd < r ? xcd * (q + 1) : r * (q + 1) + (xcd - r) * q) + i;
    bx = wg % gx;
    by = wg / gx;
}

// =======================================================================
// merged weight prep: w_proj->bf16, w_qkv->f16 hi/lo, w_fc1/2->bf16
// =======================================================================
__global__ __launch_bounds__(256)
void prep_weights(const float* __restrict__ wproj, const float* __restrict__ wqkv,
                  const float* __restrict__ wfc1, const float* __restrict__ wfc2,
                  ushort_t* __restrict__ WPROJb, ushort_t* __restrict__ Wh,
                  ushort_t* __restrict__ Wl, ushort_t* __restrict__ WFC1b,
                  ushort_t* __restrict__ WFC2b)
{
    int i = blockIdx.x * 256 + threadIdx.x;
    if (i < 147456) {
        int j = i * 4;
        float4 v = *(const float4*)(wproj + j);
        us4 o;
        o[0] = cvt_bf16(v.x); o[1] = cvt_bf16(v.y);
        o[2] = cvt_bf16(v.z); o[3] = cvt_bf16(v.w);
        *(us4*)(WPROJb + j) = o;
    } else if (i < 589824) {
        int j = (i - 147456) * 4;
        float4 v = *(const float4*)(wqkv + j);
        us4 h, l;
        #pragma unroll
        for (int k = 0; k < 4; ++k) {
            float f = (k == 0 ? v.x : k == 1 ? v.y : k == 2 ? v.z : v.w);
            h16u hh, ll;
            hh.h = (_Float16)f;
            ll.h = (_Float16)(f - (float)hh.h);
            h[k] = hh.u; l[k] = ll.u;
        }
        *(us4*)(Wh + j) = h;
        *(us4*)(Wl + j) = l;
    } else if (i < 1179648) {
        int j = (i - 589824) * 4;
        float4 v = *(const float4*)(wfc1 + j);
        us4 o;
        o[0] = cvt_bf16(v.x); o[1] = cvt_bf16(v.y);
        o[2] = cvt_bf16(v.z); o[3] = cvt_bf16(v.w);
        *(us4*)(WFC1b + j) = o;
    } else {
        int j = (i - 1179648) * 4;
        float4 v = *(const float4*)(wfc2 + j);
        us4 o;
        o[0] = cvt_bf16(v.x); o[1] = cvt_bf16(v.y);
        o[2] = cvt_bf16(v.z); o[3] = cvt_bf16(v.w);
        *(us4*)(WFC2b + j) = o;
    }
}

// =======================================================================
// LayerNorm -> bf16 (direct rows, MLP stage)
// =======================================================================
template<bool B16OUT>
__global__ __launch_bounds__(256)
void ln_kernel(const float* __restrict__ x, const float* __restrict__ g,
               const float* __restrict__ bta, void* __restrict__ y)
{
    LL row = blockIdx.x;
    const float* xr = x + row * 768;
    int t = threadIdx.x;
    float v0 = xr[t], v1 = xr[t + 256], v2 = xr[t + 512];
    __shared__ float red[256];
    red[t] = v0 + v1 + v2;
    __syncthreads();
    for (int s = 128; s; s >>= 1) { if (t < s) red[t] += red[t + s]; __syncthreads(); }
    float mean = red[0] / 768.0f;
    __syncthreads();
    float d0 = v0 - mean, d1 = v1 - mean, d2 = v2 - mean;
    red[t] = d0 * d0 + d1 * d1 + d2 * d2;
    __syncthreads();
    for (int s = 128; s; s >>= 1) { if (t < s) red[t] += red[t + s]; __syncthreads(); }
    float var = red[0] / 768.0f;
    float rs = 1.0f / sqrtf(var + 1e-5f);
    float o0 = d0 * rs * g[t]       + bta[t];
    float o1 = d1 * rs * g[t + 256] + bta[t + 256];
    float o2 = d2 * rs * g[t + 512] + bta[t + 512];
    if (B16OUT) {
        ushort_t* yr = (ushort_t*)y + row * 768;
        yr[t] = cvt_bf16(o0); yr[t + 256] = cvt_bf16(o1); yr[t + 512] = cvt_bf16(o2);
    } else {
        float* yr = (float*)y + row * 768;
        yr[t] = o0; yr[t + 256] = o1; yr[t + 512] = o2;
    }
}

// =======================================================================
// LayerNorm -> f16 hi/lo split, BOTH modalities in one launch
// =======================================================================
__global__ __launch_bounds__(256)
void ln_f16x2(const float* __restrict__ x0, const float* __restrict__ x1,
              const float* __restrict__ g, const float* __restrict__ bta,
              ushort_t* __restrict__ ybase)
{
    int row = blockIdx.x;
    int mod = row >= 10240;
    int lrow = row - mod * 10240;
    const float* xr = (mod ? x1 : x0) + (LL)lrow * 768;
    ushort_t* yh = ybase + (LL)mod * 2 * SZH + (LL)lrow * 768;
    ushort_t* yl = yh + SZH;
    int t = threadIdx.x;
    float v0 = xr[t], v1 = xr[t + 256], v2 = xr[t + 512];
    __shared__ float red[256];
    red[t] = v0 + v1 + v2;
    __syncthreads();
    for (int s = 128; s; s >>= 1) { if (t < s) red[t] += red[t + s]; __syncthreads(); }
    float mean = red[0] / 768.0f;
    __syncthreads();
    float d0 = v0 - mean, d1 = v1 - mean, d2 = v2 - mean;
    red[t] = d0 * d0 + d1 * d1 + d2 * d2;
    __syncthreads();
    for (int s = 128; s; s >>= 1) { if (t < s) red[t] += red[t + s]; __syncthreads(); }
    float var = red[0] / 768.0f;
    float rs = 1.0f / sqrtf(var + 1e-5f);
    #pragma unroll
    for (int c = 0; c < 3; ++c) {
        float d = (c == 0 ? d0 : c == 1 ? d1 : d2);
        int idx = t + c * 256;
        float o = d * rs * g[idx] + bta[idx];
        h16u hi, lo;
        hi.h = (_Float16)o;
        lo.h = (_Float16)(o - (float)hi.h);
        yh[idx] = hi.u;
        yl[idx] = lo.u;
    }
}

// =======================================================================
// QKV GEMM (VERBATIM from passing round 11)
// =======================================================================
__global__ __launch_bounds__(256)
void gemm_qkv(const ushort_t* __restrict__ Ah, const ushort_t* __restrict__ Al,
              const ushort_t* __restrict__ Bh, const ushort_t* __restrict__ Bl,
              ushort_t* __restrict__ Q1, ushort_t* __restrict__ Q2,
              ushort_t* __restrict__ K1, ushort_t* __restrict__ K2,
              ushort_t* __restrict__ Vt)
{
    __shared__ ushort_t Ahs[8192], Als[8192], Bhs[8192], Bls[8192];
    int bx, by;
    xcd_decode(bx, by);
    const int t = threadIdx.x;
    const int wave = t >> 6, lane = t & 63;
    const int wr = wave >> 1, wc = wave & 1;
    const int lr = lane & 15, lh = lane >> 4;
    const LL bm = (LL)by * 128, bn = (LL)bx * 128;
    const bool vt = (bx >= 12);

    facc acc[4][4];
    #pragma unroll
    for (int i = 0; i < 4; ++i)
        #pragma unroll
        for (int j = 0; j < 4; ++j) acc[i][j] = (facc)(0.0f);

    const LL soff = (bm + wave * 16 + (lane >> 2)) * (LL)768 + (lane & 3) * 8;
    const LL boff = (bn + wave * 16 + (lane >> 2)) * (LL)768 + (lane & 3) * 8;
    const LL a64 = (LL)64 * 768;

    GLL(Ah + soff,       &Ahs[wave * 512]);
    GLL(Ah + soff + a64, &Ahs[2048 + wave * 512]);
    GLL(Bh + boff,       &Bhs[wave * 512]);
    GLL(Bh + boff + a64, &Bhs[2048 + wave * 512]);
    if (!vt) {
        GLL(Al + soff,       &Als[wave * 512]);
        GLL(Al + soff + a64, &Als[2048 + wave * 512]);
        GLL(Bl + boff,       &Bls[wave * 512]);
        GLL(Bl + boff + a64, &Bls[2048 + wave * 512]);
    }
    __syncthreads();

    int cur = 0;
    for (int k0 = 0; k0 < 768; k0 += 32) {
        int nb = (cur ^ 1) * 4096;
        if (k0 + 32 < 768) {
            GLL(Ah + soff + k0 + 32,       &Ahs[nb + wave * 512]);
            GLL(Ah + soff + k0 + 32 + a64, &Ahs[nb + 2048 + wave * 512]);
            GLL(Bh + boff + k0 + 32,       &Bhs[nb + wave * 512]);
            GLL(Bh + boff + k0 + 32 + a64, &Bhs[nb + 2048 + wave * 512]);
            if (!vt) {
                GLL(Al + soff + k0 + 32,       &Als[nb + wave * 512]);
                GLL(Al + soff + k0 + 32 + a64, &Als[nb + 2048 + wave * 512]);
                GLL(Bl + boff + k0 + 32,       &Bls[nb + wave * 512]);
                GLL(Bl + boff + k0 + 32 + a64, &Bls[nb + 2048 + wave * 512]);
            }
        }
        int cb = cur * 4096;
        hfrag ah[4], bh[4];
        #pragma unroll
        for (int mi = 0; mi < 4; ++mi)
            ah[mi] = *(const hfrag*)&Ahs[cb + (wr * 64 + mi * 16 + lr) * 32 + lh * 8];
        #pragma unroll
        for (int ni = 0; ni < 4; ++ni)
            bh[ni] = *(const hfrag*)&Bhs[cb + (wc * 64 + ni * 16 + lr) * 32 + lh * 8];
        if (!vt) {
            hfrag al[4], bl[4];
            #pragma unroll
            for (int mi = 0; mi < 4; ++mi)
                al[mi] = *(const hfrag*)&Als[cb + (wr * 64 + mi * 16 + lr) * 32 + lh * 8];
            #pragma unroll
            for (int ni = 0; ni < 4; ++ni)
                bl[ni] = *(const hfrag*)&Bls[cb + (wc * 64 + ni * 16 + lr) * 32 + lh * 8];
            #pragma unroll
            for (int mi = 0; mi < 4; ++mi)
                #pragma unroll
                for (int ni = 0; ni < 4; ++ni) {
                    acc[mi][ni] = __builtin_amdgcn_mfma_f32_16x16x32_f16(al[mi], bh[ni], acc[mi][ni], 0, 0, 0);
                    acc[mi][ni] = __builtin_amdgcn_mfma_f32_16x16x32_f16(ah[mi], bl[ni], acc[mi][ni], 0, 0, 0);
                    acc[mi][ni] = __builtin_amdgcn_mfma_f32_16x16x32_f16(ah[mi], bh[ni], acc[mi][ni], 0, 0, 0);
                }
        } else {
            #pragma unroll
            for (int mi = 0; mi < 4; ++mi)
                #pragma unroll
                for (int ni = 0; ni < 4; ++ni)
                    acc[mi][ni] = __builtin_amdgcn_mfma_f32_16x16x32_f16(ah[mi], bh[ni], acc[mi][ni], 0, 0, 0);
        }
        __syncthreads();
        cur ^= 1;
    }

    #pragma unroll
    for (int mi = 0; mi < 4; ++mi)
        #pragma unroll
        for (int ni = 0; ni < 4; ++ni)
            #pragma unroll
            for (int j = 0; j < 4; ++j) {
                int r = (int)bm + wr * 64 + mi * 16 + lh * 4 + j;
                int c = (int)bn + wc * 64 + ni * 16 + lr;
                int b = r / 320, tt = r - b * 320;
                int s = c / 768, rem = c - s * 768;
                int h = rem >> 6, d = rem & 63;
                LL hb = (LL)(b * 12 + h) * 20480;
                float v = acc[mi][ni][j];
                if (s == 2) {
                    Vt[hb + d * 320 + tt] = cvt_bf16(v);
                } else {
                    h16u a1, a2;
                    a1.h = (_Float16)v;
                    a2.h = (_Float16)(v - (float)a1.h);
                    LL idx = hb + (LL)tt * 64 + d;
                    if (s == 0) { Q1[idx] = a1.u; Q2[idx] = a2.u; }
                    else        { K1[idx] = a1.u; K2[idx] = a2.u; }
                }
            }
}

// =======================================================================
// Fused attention (VERBATIM from passing rounds 8/10/11)
// =======================================================================
__global__ __launch_bounds__(256, 2)
void fused_attn(const ushort_t* __restrict__ Qh, const ushort_t* __restrict__ Qm,
                const ushort_t* __restrict__ Kh, const ushort_t* __restrict__ Km,
                const ushort_t* __restrict__ Vt,
                float* __restrict__ corr, ushort_t* __restrict__ attb,
                double* __restrict__ part, int mod)
{
    __shared__ __align__(128) unsigned char lds[81920];
    constexpr int PS = 40960;

    const int t = threadIdx.x;
    const int wave = t >> 6, lane = t & 63;
    const int lr = lane & 15, lh = lane >> 4;
    const int id  = blockIdx.x;
    const int xcd = id & 7;
    const int rem = id >> 3;
    const int grp = rem / 5;
    const int r0i = rem - grp * 5;
    const int bh  = grp * 8 + xcd;
    const int b = bh / 12, h = bh - b * 12;
    const int r0 = r0i * 64;
    const LL kvbase = (LL)bh * 20480;

    const LL qoff = kvbase + (LL)(r0 + wave * 16 + lr) * 64 + lh * 8;
    hfrag qh0 = *(const hfrag*)(Qh + qoff), qh1 = *(const hfrag*)(Qh + qoff + 32);
    hfrag qm0 = *(const hfrag*)(Qm + qoff), qm1 = *(const hfrag*)(Qm + qoff + 32);

    facc sacc[20];
    #pragma unroll
    for (int ct = 0; ct < 20; ++ct) sacc[ct] = (facc)(0.0f);

    #pragma unroll
    for (int ha = 0; ha < 5; ++ha) {
        if (ha) __syncthreads();
        #pragma unroll
        for (int i = 0; i < 4; ++i) {
            int id2 = wave * 4 + i;
            int s = id2 >> 3, c = id2 & 7;
            int local = c * 1024 + lane * 16;
            int row = local >> 7;
            int sb = local ^ ((row & 7) << 4);
            LL src = kvbase + (LL)ha * 4096 + (sb >> 1);
            const ushort_t* kp = (s == 0) ? Kh : Km;
            GLL(kp + src, &lds[s * 8192 + c * 1024]);
        }
        __syncthreads();

        #pragma unroll
        for (int ctl = 0; ctl < 4; ++ctl) {
            int tokl = ctl * 16 + lr;
            int x = (tokl & 7) << 4;
            const unsigned char* kb = lds + tokl * 128;
            int o0 = (lh * 16) ^ x;
            int o1 = (64 + lh * 16) ^ x;
            hfrag kh0 = *(const hfrag*)(kb + o0);
            hfrag kh1 = *(const hfrag*)(kb + o1);
            hfrag km0 = *(const hfrag*)(kb + 8192 + o0);
            hfrag km1 = *(const hfrag*)(kb + 8192 + o1);
            facc a = sacc[ha * 4 + ctl];
            a = __builtin_amdgcn_mfma_f32_16x16x32_f16(qm0, kh0, a, 0, 0, 0);
            a = __builtin_amdgcn_mfma_f32_16x16x32_f16(qh0, km0, a, 0, 0, 0);
            a = __builtin_amdgcn_mfma_f32_16x16x32_f16(qh0, kh0, a, 0, 0, 0);
            a = __builtin_amdgcn_mfma_f32_16x16x32_f16(qm1, kh1, a, 0, 0, 0);
            a = __builtin_amdgcn_mfma_f32_16x16x32_f16(qh1, km1, a, 0, 0, 0);
            a = __builtin_amdgcn_mfma_f32_16x16x32_f16(qh1, kh1, a, 0, 0, 0);
            sacc[ha * 4 + ctl] = a;
        }
    }

    __syncthreads();

    #pragma unroll
    for (int i = 0; i < 10; ++i) {
        int chunk = wave * 10 + i;
        int gs = chunk * 1024 + lane * 16;
        int d = gs / 640;
        int w = gs - d * 640;
        int sb = d * 640 + (w ^ ((d & 7) << 4));
        GLL(Vt + kvbase + (sb >> 1), &lds[chunk * 1024]);
    }

    float rs4[4];
    #pragma unroll
    for (int j = 0; j < 4; ++j) {
        float m = sacc[0][j];
        #pragma unroll
        for (int ct = 1; ct < 20; ++ct) m = fmaxf(m, sacc[ct][j]);
        #pragma unroll
        for (int o = 1; o < 16; o <<= 1) m = fmaxf(m, __shfl_xor(m, o, 64));
        m *= 0.125f;
        float s = 0.0f;
        #pragma unroll
        for (int ct = 0; ct < 20; ++ct) {
            float e = expf(sacc[ct][j] * 0.125f - m);
            sacc[ct][j] = e;
            s += e;
        }
        #pragma unroll
        for (int o = 1; o < 16; o <<= 1) s += __shfl_xor(s, o, 64);
        float rs = 1.0f / s;
        rs4[j] = rs;

        int prow = wave * 16 + lh * 4 + j;
        int xr = (prow & 7) << 4;
        #pragma unroll
        for (int ct = 0; ct < 20; ++ct) {
            int pcol = ct * 16 + lr;
            *(ushort_t*)(lds + PS + prow * 640 + ((pcol * 2) ^ xr)) =
                cvt_bf16(sacc[ct][j] * rs);
        }
    }

    __syncthreads();

    facc oacc[4];
    #pragma unroll
    for (int dt = 0; dt < 4; ++dt) oacc[dt] = (facc)(0.0f);
    int prow2 = wave * 16 + lr;
    int xp = (prow2 & 7) << 4;
    #pragma unroll
    for (int k0 = 0; k0 < 10; ++k0) {
        bfrag pa = *(const bfrag*)(lds + PS + prow2 * 640 + ((k0 * 64 + lh * 16) ^ xp));
        #pragma unroll
        for (int dt = 0; dt < 4; ++dt) {
            int dcol = dt * 16 + lr;
            bfrag vb = *(const bfrag*)(lds + dcol * 640 + ((k0 * 64 + lh * 16) ^ ((dcol & 7) << 4)));
            oacc[dt] = __builtin_amdgcn_mfma_f32_16x16x32_bf16(pa, vb, oacc[dt], 0, 0, 0);
        }
    }
    #pragma unroll
    for (int dt = 0; dt < 4; ++dt)
        #pragma unroll
        for (int j = 0; j < 4; ++j) {
            int grow = r0 + wave * 16 + lh * 4 + j;
            int gcol = h * 64 + dt * 16 + lr;
            attb[(LL)(b * 320 + grow) * 768 + gcol] = cvt_bf16(oacc[dt][j]);
        }

    __syncthreads();

    #pragma unroll
    for (int ct = 0; ct < 20; ++ct) {
        int pcol = ct * 16 + lr;
        #pragma unroll
        for (int j = 0; j < 4; ++j) {
            int prow = wave * 16 + lh * 4 + j;
            *(float*)(lds + (prow * 320 + pcol) * 4) = sacc[ct][j] * rs4[j];
        }
    }
    __syncthreads();

    float* crow = corr + (LL)bh * 102400 + (LL)r0 * 320;
    #pragma unroll
    for (int i = 0; i < 20; ++i) {
        int idx = i * 256 + t;
        int row = idx / 80, c4 = idx - row * 80;
        float4 v = *(const float4*)(lds + (row * 320 + c4 * 4) * 4);
        *(float4*)(crow + row * 320 + c4 * 4) = v;
    }

    if (r0i == 0) {
        double s64 = 0.0;
        for (int r = 0; r < 64; ++r)
            s64 += (double)*(const float*)(lds + (r * 320 + 64 + t) * 4);
        part[((LL)mod * 384 + bh) * 256 + t] = s64;
    }
}

// =======================================================================
// bf16 MFMA GEMM 16x16x32 128^2 (proj / fc1 / fc2), XCD-chunked.
// amap: optional A-row + residual-row indirection (combined-row space).
// res1: optional second residual base — rows >= 10240 read res1 at
// (row-10240) (batched-proj dual-modality residual).
// =======================================================================
template<int EPI>
__global__ __launch_bounds__(256)
void gemm_mfma(const ushort_t* __restrict__ A, const ushort_t* __restrict__ B,
               void* __restrict__ Cv, const float* __restrict__ bias,
               const float* __restrict__ res, const float* __restrict__ res1,
               const int* __restrict__ amap,
               int K, int lda, int ldb, int ldc, int ldres)
{
    __shared__ ushort_t As[8192];
    __shared__ ushort_t Bs[8192];
    int bx, by;
    xcd_decode(bx, by);
    const int t = threadIdx.x;
    const int wave = t >> 6, lane = t & 63;
    const int wr = wave >> 1, wc = wave & 1;
    const LL bm = (LL)by * 128, bn = (LL)bx * 128;

    facc acc[4][4];
    #pragma unroll
    for (int i = 0; i < 4; ++i)
        #pragma unroll
        for (int j = 0; j < 4; ++j) acc[i][j] = (facc)(0.0f);

    const int lr = lane & 15, lh = lane >> 4;
    int r1 = (int)bm + wave * 16 + (lane >> 2);
    int r2 = r1 + 64;
    if (amap) { r1 = amap[r1]; r2 = amap[r2]; }
    const ushort_t* gA1 = A + (LL)r1 * lda + (lane & 3) * 8;
    const ushort_t* gA2 = A + (LL)r2 * lda + (lane & 3) * 8;
    const ushort_t* gB = B + (bn + wave * 16 + (lane >> 2)) * ldb + (lane & 3) * 8;
    const LL b64 = (LL)64 * ldb;

    GLL(gA1,       &As[wave * 512]);
    GLL(gA2,       &As[2048 + wave * 512]);
    GLL(gB,        &Bs[wave * 512]);
    GLL(gB + b64,  &Bs[2048 + wave * 512]);
    __syncthreads();

    int cur = 0;
    for (int k0 = 0; k0 < K; k0 += 32) {
        int nb = (cur ^ 1) * 4096;
        if (k0 + 32 < K) {
            GLL(gA1 + k0 + 32,       &As[nb + wave * 512]);
            GLL(gA2 + k0 + 32,       &As[nb + 2048 + wave * 512]);
            GLL(gB + k0 + 32,        &Bs[nb + wave * 512]);
            GLL(gB + k0 + 32 + b64,  &Bs[nb + 2048 + wave * 512]);
        }
        int cb = cur * 4096;
        bfrag a[4], b[4];
        #pragma unroll
        for (int m = 0; m < 4; ++m)
            a[m] = *(const bfrag*)&As[cb + (wr * 64 + m * 16 + lr) * 32 + lh * 8];
        #pragma unroll
        for (int n = 0; n < 4; ++n)
            b[n] = *(const bfrag*)&Bs[cb + (wc * 64 + n * 16 + lr) * 32 + lh * 8];
        #pragma unroll
        for (int m = 0; m < 4; ++m)
            #pragma unroll
            for (int n = 0; n < 4; ++n)
                acc[m][n] = __builtin_amdgcn_mfma_f32_16x16x32_bf16(a[m], b[n], acc[m][n], 0, 0, 0);
        __syncthreads();
        cur ^= 1;
    }

    #pragma unroll
    for (int m = 0; m < 4; ++m) {
        #pragma unroll
        for (int n = 0; n < 4; ++n) {
            #pragma unroll
            for (int j = 0; j < 4; ++j) {
                LL r = bm + wr * 64 + m * 16 + lh * 4 + j;
                LL c = bn + wc * 64 + n * 16 + lr;
                float v = acc[m][n][j] + bias[c];
                if (EPI == 1) {
                    v = 0.5f * v * (erff(v * 0.70710678118654752f) + 1.0f);
                    ((ushort_t*)Cv)[r * ldc + c] = cvt_bf16(v);
                } else {
                    LL rr = amap ? (LL)amap[r] : r;
                    const float* rbase = res;
                    if (res1 && rr >= 10240) { rbase = res1; rr -= 10240; }
                    v += rbase[rr * ldres + c];
                    ((float*)Cv)[r * ldc + c] = v;
                }
            }
        }
    }
}

// =======================================================================
// rank_all: f64 score combine + stable rank + srcmap (both-modality,
// 15616 entries) + git/js copies
// =======================================================================
__global__ __launch_bounds__(256)
void rank_all(const double* __restrict__ part, const int* __restrict__ gis,
              const int* __restrict__ git, const float* __restrict__ js,
              int* __restrict__ srcmap, float* __restrict__ out)
{
    int b = blockIdx.x, j = threadIdx.x;
    double acc = 0.0;
    for (int h = 0; h < 12; ++h) {
        LL i0 = ((LL)(b * 12 + h)) * 256 + j;
        acc += (part[i0] + part[98304 + i0]) / 64.0;
    }
    double sj = acc / 12.0;
    __shared__ double s[256];
    __shared__ int sord[256];
    s[j] = sj;
    __syncthreads();
    int r = 0;
    for (int i = 0; i < 256; ++i) {
        double si = s[i];
        r += (si > sj) || (si == sj && i < j);
    }
    sord[r] = j;
    float gv = (float)gis[b * 256 + j];
    if (r < LKEEP) out[O_GSN + b * LKEEP + r] = gv;
    else           out[O_REM + b * LREM + (r - LKEEP)] = gv;
    __syncthreads();
    if (j < NK) {
        int src = (j < LT) ? j : (LT + sord[j - LT]);
        int v = b * NTOK + src;
        srcmap[b * NK + j] = v;
        srcmap[7808 + b * NK + j] = v + 10240;   // modality-1 rows in combined ATTb space
    }
    if (j < 64) out[O_GIT + b * 64 + j] = (float)git[b * 64 + j];
    if (b == 0 && j == 0) out[O_JS] = js[0];
}

// =======================================================================
extern "C" void kernel_launch(void* const* d_in, const int* in_sizes, int n_in,
                              void* d_out, int out_size, void* d_ws, size_t ws_size,
                              hipStream_t stream)
{
    const float* xin_m[2] = { (const float*)d_in[0], (const float*)d_in[1] };
    const int*   git    = (const int*)d_in[2];
    const int*   gis    = (const int*)d_in[3];
    const float* js     = (const float*)d_in[7];
    const float* g1     = (const float*)d_in[8];
    const float* b1     = (const float*)d_in[9];
    const float* w_qkv  = (const float*)d_in[10];
    const float* w_proj = (const float*)d_in[11];
    const float* b_proj = (const float*)d_in[12];
    const float* g2     = (const float*)d_in[13];
    const float* b2     = (const float*)d_in[14];
    const float* w_fc1  = (const float*)d_in[15];
    const float* b_fc1  = (const float*)d_in[16];
    const float* w_fc2  = (const float*)d_in[17];
    const float* b_fc2  = (const float*)d_in[18];

    float* out = (float*)d_out;
    float* ws  = (float*)d_ws;

    // overlays
    ushort_t* Xbase = (ushort_t*)(ws + W_X1);          // Xh0/Xl0/Xh1/Xl1
    float*    X1c  = ws + W_X1;                        // post-rank (X dead)
    ushort_t* ATTb0 = (ushort_t*)(ws + W_XN);
    ushort_t* ATTb1 = ATTb0 + SZH;
    ushort_t* QK  = (ushort_t*)(ws + W_QKV);
    ushort_t* Qh2 = QK,           *Qm2 = QK + SZH;
    ushort_t* Kh2 = QK + 2 * SZH, *Km2 = QK + 3 * SZH;
    ushort_t* Wh  = (ushort_t*)(ws + W_ATT);
    ushort_t* Wl  = Wh + 1769472;
    ushort_t* Vt  = (ushort_t*)(ws + W_ATT + 2000000);
    double*   part = (double*)(ws + W_ATT + 6000000);
    int*      srcmap = (int*)(ws + W_ATT + 6400000);   // 15616 ints
    ushort_t* WPROJb = (ushort_t*)(ws + W_X1G);
    ushort_t* WFC1b  = (ushort_t*)(ws + W_X1G + 294912);
    ushort_t* WFC2b  = (ushort_t*)(ws + W_X1G + 1474560);
    ushort_t* XN2b   = (ushort_t*)(ws + W_XN);         // MLP stage (ATTb dead)
    ushort_t* H1b    = (ushort_t*)(ws + W_QKV);        // MLP stage

    prep_weights<<<dim3(6912), dim3(256), 0, stream>>>(
        w_proj, w_qkv, w_fc1, w_fc2, WPROJb, Wh, Wl, WFC1b, WFC2b);

    ln_f16x2<<<dim3(2 * BATCH * NTOK), dim3(256), 0, stream>>>(
        xin_m[0], xin_m[1], g1, b1, Xbase);

    for (int m = 0; m < 2; ++m) {
        float* corr = out + (m ? O_CT : O_CR);
        ushort_t* ATTbm = m ? ATTb1 : ATTb0;
        ushort_t* Xh = Xbase + (LL)m * 2 * SZH;
        ushort_t* Xl = Xh + SZH;

        gemm_qkv<<<dim3(18, 80), dim3(256), 0, stream>>>(
            Xh, Xl, Wh, Wl, Qh2, Qm2, Kh2, Km2, Vt);

        fused_attn<<<dim3(1920), dim3(256), 0, stream>>>(
            Qh2, Qm2, Kh2, Km2, Vt, corr, ATTbm, part, m);
    }

    rank_all<<<dim3(BATCH), dim3(256), 0, stream>>>(part, gis, git, js, srcmap, out);

    // proj, BOTH modalities in one launch (ATTb0/ATTb1 contiguous; combined
    // amap rows; residual picks xin0/xin1 by combined row)
    gemm_mfma<2><<<dim3(6, 122), dim3(256), 0, stream>>>(
        ATTb0, WPROJb, X1c, b_proj, xin_m[0], xin_m[1], srcmap,
        768, 768, 768, 768, 768);

    ln_kernel<true><<<dim3(2 * BATCH * NK), dim3(256), 0, stream>>>(
        X1c, g2, b2, XN2b);

    gemm_mfma<1><<<dim3(24, 122), dim3(256), 0, stream>>>(
        XN2b, WFC1b, H1b, b_fc1, nullptr, nullptr, nullptr, 768, 768, 768, 3072, 0);

    gemm_mfma<2><<<dim3(6, 122), dim3(256), 0, stream>>>(
        H1b, WFC2b, out + O_XRGB, b_fc2, X1c, nullptr, nullptr,
        3072, 3072, 3072, 768, 768);
}

// Round 15
// 845.538 us; speedup vs baseline: 1.1618x; 1.0394x over previous
//
#include <hip/hip_runtime.h>

typedef long long LL;
typedef unsigned short ushort_t;
typedef __attribute__((ext_vector_type(8))) short bfrag;      // 8 bf16
typedef __attribute__((ext_vector_type(8))) _Float16 hfrag;   // 8 f16
typedef __attribute__((ext_vector_type(4))) float facc;
typedef __attribute__((ext_vector_type(4))) unsigned short us4;

// ---- problem constants ----
constexpr int CDIM  = 768;
constexpr int HEADS = 12;
constexpr int LT    = 64;
constexpr int NTOK  = 320;
constexpr int BATCH = 32;
constexpr int LKEEP = 180;
constexpr int LREM  = 76;
constexpr int NK    = 244;

// ---- d_out element offsets (all f32) ----
constexpr LL O_XRGB = 0;
constexpr LL O_XTIR = 5996544;
constexpr LL O_GIT  = 11993088;
constexpr LL O_GSN  = 11995136;
constexpr LL O_REM  = 12000896;
constexpr LL O_CR   = 12003328;
constexpr LL O_CT   = 51324928;
constexpr LL O_JS   = 90646528;

// ---- workspace float offsets ----
constexpr LL W_X1   = 0;          // Xh0/Xl0/Xh1/Xl1 (attn) -> X1c f32 compact (post-rank)
constexpr LL W_X1G  = 15728640;   // WPROJb | WFC1b(+294912) | WFC2b(+1474560)
constexpr LL W_XN   = 27746304;   // ATTb[0], ATTb[1] (2 x SZH ushort) -> XN2b (MLP)
constexpr LL W_QKV  = 35610624;   // Qh/Qm/Kh/Km (4 x SZH ushort) | H1b(batched)
constexpr LL W_ATT  = 59596800;   // Wh/Wl | Vt(+2000000) | part(+6000000) | srcmap(+6400000)

constexpr LL SZH = 7864320;

__device__ inline ushort_t cvt_bf16(float f) {
    union { float f; unsigned u; } x; x.f = f;
    unsigned u = x.u + 0x7fffu + ((x.u >> 16) & 1u);
    return (ushort_t)(u >> 16);
}
union h16u { _Float16 h; ushort_t u; };

#define GLL(gp, lp) __builtin_amdgcn_global_load_lds( \
    (const __attribute__((address_space(1))) unsigned int*)(gp), \
    (__attribute__((address_space(3))) unsigned int*)(lp), 16, 0, 0)

// bijective XCD-chunked decode (m204): same-by blocks land on one XCD
__device__ inline void xcd_decode(int& bx, int& by) {
    int gx = gridDim.x;
    int nwg = gx * gridDim.y;
    int bid = blockIdx.y * gx + blockIdx.x;
    int q = nwg >> 3, r = nwg & 7;
    int xcd = bid & 7, i = bid >> 3;
    int wg = (xcd < r ? xcd * (q + 1) : r * (q + 1) + (xcd - r) * q) + i;
    bx = wg % gx;
    by = wg / gx;
}

// =======================================================================
// merged weight prep: w_proj->bf16, w_qkv->f16 hi/lo, w_fc1/2->bf16
// =======================================================================
__global__ __launch_bounds__(256)
void prep_weights(const float* __restrict__ wproj, const float* __restrict__ wqkv,
                  const float* __restrict__ wfc1, const float* __restrict__ wfc2,
                  ushort_t* __restrict__ WPROJb, ushort_t* __restrict__ Wh,
                  ushort_t* __restrict__ Wl, ushort_t* __restrict__ WFC1b,
                  ushort_t* __restrict__ WFC2b)
{
    int i = blockIdx.x * 256 + threadIdx.x;
    if (i < 147456) {
        int j = i * 4;
        float4 v = *(const float4*)(wproj + j);
        us4 o;
        o[0] = cvt_bf16(v.x); o[1] = cvt_bf16(v.y);
        o[2] = cvt_bf16(v.z); o[3] = cvt_bf16(v.w);
        *(us4*)(WPROJb + j) = o;
    } else if (i < 589824) {
        int j = (i - 147456) * 4;
        float4 v = *(const float4*)(wqkv + j);
        us4 h, l;
        #pragma unroll
        for (int k = 0; k < 4; ++k) {
            float f = (k == 0 ? v.x : k == 1 ? v.y : k == 2 ? v.z : v.w);
            h16u hh, ll;
            hh.h = (_Float16)f;
            ll.h = (_Float16)(f - (float)hh.h);
            h[k] = hh.u; l[k] = ll.u;
        }
        *(us4*)(Wh + j) = h;
        *(us4*)(Wl + j) = l;
    } else if (i < 1179648) {
        int j = (i - 589824) * 4;
        float4 v = *(const float4*)(wfc1 + j);
        us4 o;
        o[0] = cvt_bf16(v.x); o[1] = cvt_bf16(v.y);
        o[2] = cvt_bf16(v.z); o[3] = cvt_bf16(v.w);
        *(us4*)(WFC1b + j) = o;
    } else {
        int j = (i - 1179648) * 4;
        float4 v = *(const float4*)(wfc2 + j);
        us4 o;
        o[0] = cvt_bf16(v.x); o[1] = cvt_bf16(v.y);
        o[2] = cvt_bf16(v.z); o[3] = cvt_bf16(v.w);
        *(us4*)(WFC2b + j) = o;
    }
}

// =======================================================================
// LayerNorm -> bf16 (direct rows, MLP stage)
// =======================================================================
template<bool B16OUT>
__global__ __launch_bounds__(256)
void ln_kernel(const float* __restrict__ x, const float* __restrict__ g,
               const float* __restrict__ bta, void* __restrict__ y)
{
    LL row = blockIdx.x;
    const float* xr = x + row * 768;
    int t = threadIdx.x;
    float v0 = xr[t], v1 = xr[t + 256], v2 = xr[t + 512];
    __shared__ float red[256];
    red[t] = v0 + v1 + v2;
    __syncthreads();
    for (int s = 128; s; s >>= 1) { if (t < s) red[t] += red[t + s]; __syncthreads(); }
    float mean = red[0] / 768.0f;
    __syncthreads();
    float d0 = v0 - mean, d1 = v1 - mean, d2 = v2 - mean;
    red[t] = d0 * d0 + d1 * d1 + d2 * d2;
    __syncthreads();
    for (int s = 128; s; s >>= 1) { if (t < s) red[t] += red[t + s]; __syncthreads(); }
    float var = red[0] / 768.0f;
    float rs = 1.0f / sqrtf(var + 1e-5f);
    float o0 = d0 * rs * g[t]       + bta[t];
    float o1 = d1 * rs * g[t + 256] + bta[t + 256];
    float o2 = d2 * rs * g[t + 512] + bta[t + 512];
    if (B16OUT) {
        ushort_t* yr = (ushort_t*)y + row * 768;
        yr[t] = cvt_bf16(o0); yr[t + 256] = cvt_bf16(o1); yr[t + 512] = cvt_bf16(o2);
    } else {
        float* yr = (float*)y + row * 768;
        yr[t] = o0; yr[t + 256] = o1; yr[t + 512] = o2;
    }
}

// =======================================================================
// LayerNorm -> f16 hi/lo split, BOTH modalities in one launch
// =======================================================================
__global__ __launch_bounds__(256)
void ln_f16x2(const float* __restrict__ x0, const float* __restrict__ x1,
              const float* __restrict__ g, const float* __restrict__ bta,
              ushort_t* __restrict__ ybase)
{
    int row = blockIdx.x;
    int mod = row >= 10240;
    int lrow = row - mod * 10240;
    const float* xr = (mod ? x1 : x0) + (LL)lrow * 768;
    ushort_t* yh = ybase + (LL)mod * 2 * SZH + (LL)lrow * 768;
    ushort_t* yl = yh + SZH;
    int t = threadIdx.x;
    float v0 = xr[t], v1 = xr[t + 256], v2 = xr[t + 512];
    __shared__ float red[256];
    red[t] = v0 + v1 + v2;
    __syncthreads();
    for (int s = 128; s; s >>= 1) { if (t < s) red[t] += red[t + s]; __syncthreads(); }
    float mean = red[0] / 768.0f;
    __syncthreads();
    float d0 = v0 - mean, d1 = v1 - mean, d2 = v2 - mean;
    red[t] = d0 * d0 + d1 * d1 + d2 * d2;
    __syncthreads();
    for (int s = 128; s; s >>= 1) { if (t < s) red[t] += red[t + s]; __syncthreads(); }
    float var = red[0] / 768.0f;
    float rs = 1.0f / sqrtf(var + 1e-5f);
    #pragma unroll
    for (int c = 0; c < 3; ++c) {
        float d = (c == 0 ? d0 : c == 1 ? d1 : d2);
        int idx = t + c * 256;
        float o = d * rs * g[idx] + bta[idx];
        h16u hi, lo;
        hi.h = (_Float16)o;
        lo.h = (_Float16)(o - (float)hi.h);
        yh[idx] = hi.u;
        yl[idx] = lo.u;
    }
}

// =======================================================================
// Q/K GEMM: pure 3-pass split-f16, N=1536.
// Epilogue: s = (c>=768) — FIXED classification (round-14 bug: c>>9).
// =======================================================================
__global__ __launch_bounds__(256)
void gemm_qk(const ushort_t* __restrict__ Ah, const ushort_t* __restrict__ Al,
             const ushort_t* __restrict__ Bh, const ushort_t* __restrict__ Bl,
             ushort_t* __restrict__ Q1, ushort_t* __restrict__ Q2,
             ushort_t* __restrict__ K1, ushort_t* __restrict__ K2)
{
    __shared__ ushort_t Ahs[8192], Als[8192], Bhs[8192], Bls[8192];
    int bx, by;
    xcd_decode(bx, by);
    const int t = threadIdx.x;
    const int wave = t >> 6, lane = t & 63;
    const int wr = wave >> 1, wc = wave & 1;
    const int lr = lane & 15, lh = lane >> 4;
    const LL bm = (LL)by * 128, bn = (LL)bx * 128;

    facc acc[4][4];
    #pragma unroll
    for (int i = 0; i < 4; ++i)
        #pragma unroll
        for (int j = 0; j < 4; ++j) acc[i][j] = (facc)(0.0f);

    const LL soff = (bm + wave * 16 + (lane >> 2)) * (LL)768 + (lane & 3) * 8;
    const LL boff = (bn + wave * 16 + (lane >> 2)) * (LL)768 + (lane & 3) * 8;
    const LL a64 = (LL)64 * 768;

    GLL(Ah + soff,       &Ahs[wave * 512]);
    GLL(Ah + soff + a64, &Ahs[2048 + wave * 512]);
    GLL(Bh + boff,       &Bhs[wave * 512]);
    GLL(Bh + boff + a64, &Bhs[2048 + wave * 512]);
    GLL(Al + soff,       &Als[wave * 512]);
    GLL(Al + soff + a64, &Als[2048 + wave * 512]);
    GLL(Bl + boff,       &Bls[wave * 512]);
    GLL(Bl + boff + a64, &Bls[2048 + wave * 512]);
    __syncthreads();

    int cur = 0;
    for (int k0 = 0; k0 < 768; k0 += 32) {
        int nb = (cur ^ 1) * 4096;
        if (k0 + 32 < 768) {
            GLL(Ah + soff + k0 + 32,       &Ahs[nb + wave * 512]);
            GLL(Ah + soff + k0 + 32 + a64, &Ahs[nb + 2048 + wave * 512]);
            GLL(Bh + boff + k0 + 32,       &Bhs[nb + wave * 512]);
            GLL(Bh + boff + k0 + 32 + a64, &Bhs[nb + 2048 + wave * 512]);
            GLL(Al + soff + k0 + 32,       &Als[nb + wave * 512]);
            GLL(Al + soff + k0 + 32 + a64, &Als[nb + 2048 + wave * 512]);
            GLL(Bl + boff + k0 + 32,       &Bls[nb + wave * 512]);
            GLL(Bl + boff + k0 + 32 + a64, &Bls[nb + 2048 + wave * 512]);
        }
        int cb = cur * 4096;
        hfrag ah[4], bh[4], al[4], bl[4];
        #pragma unroll
        for (int mi = 0; mi < 4; ++mi) {
            int off = cb + (wr * 64 + mi * 16 + lr) * 32 + lh * 8;
            ah[mi] = *(const hfrag*)&Ahs[off];
            al[mi] = *(const hfrag*)&Als[off];
        }
        #pragma unroll
        for (int ni = 0; ni < 4; ++ni) {
            int off = cb + (wc * 64 + ni * 16 + lr) * 32 + lh * 8;
            bh[ni] = *(const hfrag*)&Bhs[off];
            bl[ni] = *(const hfrag*)&Bls[off];
        }
        #pragma unroll
        for (int mi = 0; mi < 4; ++mi)
            #pragma unroll
            for (int ni = 0; ni < 4; ++ni) {
                acc[mi][ni] = __builtin_amdgcn_mfma_f32_16x16x32_f16(al[mi], bh[ni], acc[mi][ni], 0, 0, 0);
                acc[mi][ni] = __builtin_amdgcn_mfma_f32_16x16x32_f16(ah[mi], bl[ni], acc[mi][ni], 0, 0, 0);
                acc[mi][ni] = __builtin_amdgcn_mfma_f32_16x16x32_f16(ah[mi], bh[ni], acc[mi][ni], 0, 0, 0);
            }
        __syncthreads();
        cur ^= 1;
    }

    #pragma unroll
    for (int mi = 0; mi < 4; ++mi)
        #pragma unroll
        for (int ni = 0; ni < 4; ++ni)
            #pragma unroll
            for (int j = 0; j < 4; ++j) {
                int r = (int)bm + wr * 64 + mi * 16 + lh * 4 + j;
                int c = (int)bn + wc * 64 + ni * 16 + lr;
                int b = r / 320, tt = r - b * 320;
                int s = (c >= 768) ? 1 : 0;
                int rem = c - s * 768;
                int h = rem >> 6, d = rem & 63;
                LL hb = (LL)(b * 12 + h) * 20480;
                float v = acc[mi][ni][j];
                h16u a1, a2;
                a1.h = (_Float16)v;
                a2.h = (_Float16)(v - (float)a1.h);
                LL idx = hb + (LL)tt * 64 + d;
                if (s == 0) { Q1[idx] = a1.u; Q2[idx] = a2.u; }
                else        { K1[idx] = a1.u; K2[idx] = a2.u; }
            }
}

// =======================================================================
// V GEMM: single-pass f16 (Xh x WhV), N=768, lean LDS (16KB) -> high occ.
// Epilogue: V bf16 transposed [b,h,64,t].
// =======================================================================
__global__ __launch_bounds__(256)
void gemm_v(const ushort_t* __restrict__ Ah, const ushort_t* __restrict__ Bh,
            ushort_t* __restrict__ Vt)
{
    __shared__ ushort_t Ahs[8192], Bhs[8192];
    int bx, by;
    xcd_decode(bx, by);
    const int t = threadIdx.x;
    const int wave = t >> 6, lane = t & 63;
    const int wr = wave >> 1, wc = wave & 1;
    const int lr = lane & 15, lh = lane >> 4;
    const LL bm = (LL)by * 128, bn = (LL)bx * 128;

    facc acc[4][4];
    #pragma unroll
    for (int i = 0; i < 4; ++i)
        #pragma unroll
        for (int j = 0; j < 4; ++j) acc[i][j] = (facc)(0.0f);

    const LL soff = (bm + wave * 16 + (lane >> 2)) * (LL)768 + (lane & 3) * 8;
    const LL boff = (bn + wave * 16 + (lane >> 2)) * (LL)768 + (lane & 3) * 8;
    const LL a64 = (LL)64 * 768;

    GLL(Ah + soff,       &Ahs[wave * 512]);
    GLL(Ah + soff + a64, &Ahs[2048 + wave * 512]);
    GLL(Bh + boff,       &Bhs[wave * 512]);
    GLL(Bh + boff + a64, &Bhs[2048 + wave * 512]);
    __syncthreads();

    int cur = 0;
    for (int k0 = 0; k0 < 768; k0 += 32) {
        int nb = (cur ^ 1) * 4096;
        if (k0 + 32 < 768) {
            GLL(Ah + soff + k0 + 32,       &Ahs[nb + wave * 512]);
            GLL(Ah + soff + k0 + 32 + a64, &Ahs[nb + 2048 + wave * 512]);
            GLL(Bh + boff + k0 + 32,       &Bhs[nb + wave * 512]);
            GLL(Bh + boff + k0 + 32 + a64, &Bhs[nb + 2048 + wave * 512]);
        }
        int cb = cur * 4096;
        hfrag ah[4], bh[4];
        #pragma unroll
        for (int mi = 0; mi < 4; ++mi)
            ah[mi] = *(const hfrag*)&Ahs[cb + (wr * 64 + mi * 16 + lr) * 32 + lh * 8];
        #pragma unroll
        for (int ni = 0; ni < 4; ++ni)
            bh[ni] = *(const hfrag*)&Bhs[cb + (wc * 64 + ni * 16 + lr) * 32 + lh * 8];
        #pragma unroll
        for (int mi = 0; mi < 4; ++mi)
            #pragma unroll
            for (int ni = 0; ni < 4; ++ni)
                acc[mi][ni] = __builtin_amdgcn_mfma_f32_16x16x32_f16(ah[mi], bh[ni], acc[mi][ni], 0, 0, 0);
        __syncthreads();
        cur ^= 1;
    }

    #pragma unroll
    for (int mi = 0; mi < 4; ++mi)
        #pragma unroll
        for (int ni = 0; ni < 4; ++ni)
            #pragma unroll
            for (int j = 0; j < 4; ++j) {
                int r = (int)bm + wr * 64 + mi * 16 + lh * 4 + j;
                int c = (int)bn + wc * 64 + ni * 16 + lr;
                int b = r / 320, tt = r - b * 320;
                int h = c >> 6, d = c & 63;
                Vt[(LL)(b * 12 + h) * 20480 + d * 320 + tt] = cvt_bf16(acc[mi][ni][j]);
            }
}

// =======================================================================
// Fused attention (VERBATIM from passing rounds 8/10/11/13)
// =======================================================================
__global__ __launch_bounds__(256, 2)
void fused_attn(const ushort_t* __restrict__ Qh, const ushort_t* __restrict__ Qm,
                const ushort_t* __restrict__ Kh, const ushort_t* __restrict__ Km,
                const ushort_t* __restrict__ Vt,
                float* __restrict__ corr, ushort_t* __restrict__ attb,
                double* __restrict__ part, int mod)
{
    __shared__ __align__(128) unsigned char lds[81920];
    constexpr int PS = 40960;

    const int t = threadIdx.x;
    const int wave = t >> 6, lane = t & 63;
    const int lr = lane & 15, lh = lane >> 4;
    const int id  = blockIdx.x;
    const int xcd = id & 7;
    const int rem = id >> 3;
    const int grp = rem / 5;
    const int r0i = rem - grp * 5;
    const int bh  = grp * 8 + xcd;
    const int b = bh / 12, h = bh - b * 12;
    const int r0 = r0i * 64;
    const LL kvbase = (LL)bh * 20480;

    const LL qoff = kvbase + (LL)(r0 + wave * 16 + lr) * 64 + lh * 8;
    hfrag qh0 = *(const hfrag*)(Qh + qoff), qh1 = *(const hfrag*)(Qh + qoff + 32);
    hfrag qm0 = *(const hfrag*)(Qm + qoff), qm1 = *(const hfrag*)(Qm + qoff + 32);

    facc sacc[20];
    #pragma unroll
    for (int ct = 0; ct < 20; ++ct) sacc[ct] = (facc)(0.0f);

    #pragma unroll
    for (int ha = 0; ha < 5; ++ha) {
        if (ha) __syncthreads();
        #pragma unroll
        for (int i = 0; i < 4; ++i) {
            int id2 = wave * 4 + i;
            int s = id2 >> 3, c = id2 & 7;
            int local = c * 1024 + lane * 16;
            int row = local >> 7;
            int sb = local ^ ((row & 7) << 4);
            LL src = kvbase + (LL)ha * 4096 + (sb >> 1);
            const ushort_t* kp = (s == 0) ? Kh : Km;
            GLL(kp + src, &lds[s * 8192 + c * 1024]);
        }
        __syncthreads();

        #pragma unroll
        for (int ctl = 0; ctl < 4; ++ctl) {
            int tokl = ctl * 16 + lr;
            int x = (tokl & 7) << 4;
            const unsigned char* kb = lds + tokl * 128;
            int o0 = (lh * 16) ^ x;
            int o1 = (64 + lh * 16) ^ x;
            hfrag kh0 = *(const hfrag*)(kb + o0);
            hfrag kh1 = *(const hfrag*)(kb + o1);
            hfrag km0 = *(const hfrag*)(kb + 8192 + o0);
            hfrag km1 = *(const hfrag*)(kb + 8192 + o1);
            facc a = sacc[ha * 4 + ctl];
            a = __builtin_amdgcn_mfma_f32_16x16x32_f16(qm0, kh0, a, 0, 0, 0);
            a = __builtin_amdgcn_mfma_f32_16x16x32_f16(qh0, km0, a, 0, 0, 0);
            a = __builtin_amdgcn_mfma_f32_16x16x32_f16(qh0, kh0, a, 0, 0, 0);
            a = __builtin_amdgcn_mfma_f32_16x16x32_f16(qm1, kh1, a, 0, 0, 0);
            a = __builtin_amdgcn_mfma_f32_16x16x32_f16(qh1, km1, a, 0, 0, 0);
            a = __builtin_amdgcn_mfma_f32_16x16x32_f16(qh1, kh1, a, 0, 0, 0);
            sacc[ha * 4 + ctl] = a;
        }
    }

    __syncthreads();

    #pragma unroll
    for (int i = 0; i < 10; ++i) {
        int chunk = wave * 10 + i;
        int gs = chunk * 1024 + lane * 16;
        int d = gs / 640;
        int w = gs - d * 640;
        int sb = d * 640 + (w ^ ((d & 7) << 4));
        GLL(Vt + kvbase + (sb >> 1), &lds[chunk * 1024]);
    }

    float rs4[4];
    #pragma unroll
    for (int j = 0; j < 4; ++j) {
        float m = sacc[0][j];
        #pragma unroll
        for (int ct = 1; ct < 20; ++ct) m = fmaxf(m, sacc[ct][j]);
        #pragma unroll
        for (int o = 1; o < 16; o <<= 1) m = fmaxf(m, __shfl_xor(m, o, 64));
        m *= 0.125f;
        float s = 0.0f;
        #pragma unroll
        for (int ct = 0; ct < 20; ++ct) {
            float e = expf(sacc[ct][j] * 0.125f - m);
            sacc[ct][j] = e;
            s += e;
        }
        #pragma unroll
        for (int o = 1; o < 16; o <<= 1) s += __shfl_xor(s, o, 64);
        float rs = 1.0f / s;
        rs4[j] = rs;

        int prow = wave * 16 + lh * 4 + j;
        int xr = (prow & 7) << 4;
        #pragma unroll
        for (int ct = 0; ct < 20; ++ct) {
            int pcol = ct * 16 + lr;
            *(ushort_t*)(lds + PS + prow * 640 + ((pcol * 2) ^ xr)) =
                cvt_bf16(sacc[ct][j] * rs);
        }
    }

    __syncthreads();

    facc oacc[4];
    #pragma unroll
    for (int dt = 0; dt < 4; ++dt) oacc[dt] = (facc)(0.0f);
    int prow2 = wave * 16 + lr;
    int xp = (prow2 & 7) << 4;
    #pragma unroll
    for (int k0 = 0; k0 < 10; ++k0) {
        bfrag pa = *(const bfrag*)(lds + PS + prow2 * 640 + ((k0 * 64 + lh * 16) ^ xp));
        #pragma unroll
        for (int dt = 0; dt < 4; ++dt) {
            int dcol = dt * 16 + lr;
            bfrag vb = *(const bfrag*)(lds + dcol * 640 + ((k0 * 64 + lh * 16) ^ ((dcol & 7) << 4)));
            oacc[dt] = __builtin_amdgcn_mfma_f32_16x16x32_bf16(pa, vb, oacc[dt], 0, 0, 0);
        }
    }
    #pragma unroll
    for (int dt = 0; dt < 4; ++dt)
        #pragma unroll
        for (int j = 0; j < 4; ++j) {
            int grow = r0 + wave * 16 + lh * 4 + j;
            int gcol = h * 64 + dt * 16 + lr;
            attb[(LL)(b * 320 + grow) * 768 + gcol] = cvt_bf16(oacc[dt][j]);
        }

    __syncthreads();

    #pragma unroll
    for (int ct = 0; ct < 20; ++ct) {
        int pcol = ct * 16 + lr;
        #pragma unroll
        for (int j = 0; j < 4; ++j) {
            int prow = wave * 16 + lh * 4 + j;
            *(float*)(lds + (prow * 320 + pcol) * 4) = sacc[ct][j] * rs4[j];
        }
    }
    __syncthreads();

    float* crow = corr + (LL)bh * 102400 + (LL)r0 * 320;
    #pragma unroll
    for (int i = 0; i < 20; ++i) {
        int idx = i * 256 + t;
        int row = idx / 80, c4 = idx - row * 80;
        float4 v = *(const float4*)(lds + (row * 320 + c4 * 4) * 4);
        *(float4*)(crow + row * 320 + c4 * 4) = v;
    }

    if (r0i == 0) {
        double s64 = 0.0;
        for (int r = 0; r < 64; ++r)
            s64 += (double)*(const float*)(lds + (r * 320 + 64 + t) * 4);
        part[((LL)mod * 384 + bh) * 256 + t] = s64;
    }
}

// =======================================================================
// bf16 MFMA GEMM 16x16x32 128^2 (proj / fc1 / fc2), XCD-chunked.
// amap: optional A-row + residual-row indirection (combined-row space).
// res1: optional second residual base for rows >= 10240.
// =======================================================================
template<int EPI>
__global__ __launch_bounds__(256)
void gemm_mfma(const ushort_t* __restrict__ A, const ushort_t* __restrict__ B,
               void* __restrict__ Cv, const float* __restrict__ bias,
               const float* __restrict__ res, const float* __restrict__ res1,
               const int* __restrict__ amap,
               int K, int lda, int ldb, int ldc, int ldres)
{
    __shared__ ushort_t As[8192];
    __shared__ ushort_t Bs[8192];
    int bx, by;
    xcd_decode(bx, by);
    const int t = threadIdx.x;
    const int wave = t >> 6, lane = t & 63;
    const int wr = wave >> 1, wc = wave & 1;
    const LL bm = (LL)by * 128, bn = (LL)bx * 128;

    facc acc[4][4];
    #pragma unroll
    for (int i = 0; i < 4; ++i)
        #pragma unroll
        for (int j = 0; j < 4; ++j) acc[i][j] = (facc)(0.0f);

    const int lr = lane & 15, lh = lane >> 4;
    int r1 = (int)bm + wave * 16 + (lane >> 2);
    int r2 = r1 + 64;
    if (amap) { r1 = amap[r1]; r2 = amap[r2]; }
    const ushort_t* gA1 = A + (LL)r1 * lda + (lane & 3) * 8;
    const ushort_t* gA2 = A + (LL)r2 * lda + (lane & 3) * 8;
    const ushort_t* gB = B + (bn + wave * 16 + (lane >> 2)) * ldb + (lane & 3) * 8;
    const LL b64 = (LL)64 * ldb;

    GLL(gA1,       &As[wave * 512]);
    GLL(gA2,       &As[2048 + wave * 512]);
    GLL(gB,        &Bs[wave * 512]);
    GLL(gB + b64,  &Bs[2048 + wave * 512]);
    __syncthreads();

    int cur = 0;
    for (int k0 = 0; k0 < K; k0 += 32) {
        int nb = (cur ^ 1) * 4096;
        if (k0 + 32 < K) {
            GLL(gA1 + k0 + 32,       &As[nb + wave * 512]);
            GLL(gA2 + k0 + 32,       &As[nb + 2048 + wave * 512]);
            GLL(gB + k0 + 32,        &Bs[nb + wave * 512]);
            GLL(gB + k0 + 32 + b64,  &Bs[nb + 2048 + wave * 512]);
        }
        int cb = cur * 4096;
        bfrag a[4], b[4];
        #pragma unroll
        for (int m = 0; m < 4; ++m)
            a[m] = *(const bfrag*)&As[cb + (wr * 64 + m * 16 + lr) * 32 + lh * 8];
        #pragma unroll
        for (int n = 0; n < 4; ++n)
            b[n] = *(const bfrag*)&Bs[cb + (wc * 64 + n * 16 + lr) * 32 + lh * 8];
        #pragma unroll
        for (int m = 0; m < 4; ++m)
            #pragma unroll
            for (int n = 0; n < 4; ++n)
                acc[m][n] = __builtin_amdgcn_mfma_f32_16x16x32_bf16(a[m], b[n], acc[m][n], 0, 0, 0);
        __syncthreads();
        cur ^= 1;
    }

    #pragma unroll
    for (int m = 0; m < 4; ++m) {
        #pragma unroll
        for (int n = 0; n < 4; ++n) {
            #pragma unroll
            for (int j = 0; j < 4; ++j) {
                LL r = bm + wr * 64 + m * 16 + lh * 4 + j;
                LL c = bn + wc * 64 + n * 16 + lr;
                float v = acc[m][n][j] + bias[c];
                if (EPI == 1) {
                    v = 0.5f * v * (erff(v * 0.70710678118654752f) + 1.0f);
                    ((ushort_t*)Cv)[r * ldc + c] = cvt_bf16(v);
                } else {
                    LL rr = amap ? (LL)amap[r] : r;
                    const float* rbase = res;
                    if (res1 && rr >= 10240) { rbase = res1; rr -= 10240; }
                    v += rbase[rr * ldres + c];
                    ((float*)Cv)[r * ldc + c] = v;
                }
            }
        }
    }
}

// =======================================================================
// rank_all: f64 score combine + stable rank + srcmap (both-modality)
// + git/js copies
// =======================================================================
__global__ __launch_bounds__(256)
void rank_all(const double* __restrict__ part, const int* __restrict__ gis,
              const int* __restrict__ git, const float* __restrict__ js,
              int* __restrict__ srcmap, float* __restrict__ out)
{
    int b = blockIdx.x, j = threadIdx.x;
    double acc = 0.0;
    for (int h = 0; h < 12; ++h) {
        LL i0 = ((LL)(b * 12 + h)) * 256 + j;
        acc += (part[i0] + part[98304 + i0]) / 64.0;
    }
    double sj = acc / 12.0;
    __shared__ double s[256];
    __shared__ int sord[256];
    s[j] = sj;
    __syncthreads();
    int r = 0;
    for (int i = 0; i < 256; ++i) {
        double si = s[i];
        r += (si > sj) || (si == sj && i < j);
    }
    sord[r] = j;
    float gv = (float)gis[b * 256 + j];
    if (r < LKEEP) out[O_GSN + b * LKEEP + r] = gv;
    else           out[O_REM + b * LREM + (r - LKEEP)] = gv;
    __syncthreads();
    if (j < NK) {
        int src = (j < LT) ? j : (LT + sord[j - LT]);
        int v = b * NTOK + src;
        srcmap[b * NK + j] = v;
        srcmap[7808 + b * NK + j] = v + 10240;
    }
    if (j < 64) out[O_GIT + b * 64 + j] = (float)git[b * 64 + j];
    if (b == 0 && j == 0) out[O_JS] = js[0];
}

// =======================================================================
extern "C" void kernel_launch(void* const* d_in, const int* in_sizes, int n_in,
                              void* d_out, int out_size, void* d_ws, size_t ws_size,
                              hipStream_t stream)
{
    const float* xin_m[2] = { (const float*)d_in[0], (const float*)d_in[1] };
    const int*   git    = (const int*)d_in[2];
    const int*   gis    = (const int*)d_in[3];
    const float* js     = (const float*)d_in[7];
    const float* g1     = (const float*)d_in[8];
    const float* b1     = (const float*)d_in[9];
    const float* w_qkv  = (const float*)d_in[10];
    const float* w_proj = (const float*)d_in[11];
    const float* b_proj = (const float*)d_in[12];
    const float* g2     = (const float*)d_in[13];
    const float* b2     = (const float*)d_in[14];
    const float* w_fc1  = (const float*)d_in[15];
    const float* b_fc1  = (const float*)d_in[16];
    const float* w_fc2  = (const float*)d_in[17];
    const float* b_fc2  = (const float*)d_in[18];

    float* out = (float*)d_out;
    float* ws  = (float*)d_ws;

    // overlays
    ushort_t* Xbase = (ushort_t*)(ws + W_X1);          // Xh0/Xl0/Xh1/Xl1
    float*    X1c  = ws + W_X1;                        // post-rank (X dead)
    ushort_t* ATTb0 = (ushort_t*)(ws + W_XN);
    ushort_t* ATTb1 = ATTb0 + SZH;
    ushort_t* QK  = (ushort_t*)(ws + W_QKV);
    ushort_t* Qh2 = QK,           *Qm2 = QK + SZH;
    ushort_t* Kh2 = QK + 2 * SZH, *Km2 = QK + 3 * SZH;
    ushort_t* Wh  = (ushort_t*)(ws + W_ATT);
    ushort_t* Wl  = Wh + 1769472;
    ushort_t* Vt  = (ushort_t*)(ws + W_ATT + 2000000);
    double*   part = (double*)(ws + W_ATT + 6000000);
    int*      srcmap = (int*)(ws + W_ATT + 6400000);   // 15616 ints
    ushort_t* WPROJb = (ushort_t*)(ws + W_X1G);
    ushort_t* WFC1b  = (ushort_t*)(ws + W_X1G + 294912);
    ushort_t* WFC2b  = (ushort_t*)(ws + W_X1G + 1474560);
    ushort_t* XN2b   = (ushort_t*)(ws + W_XN);         // MLP stage (ATTb dead)
    ushort_t* H1b    = (ushort_t*)(ws + W_QKV);        // MLP stage

    prep_weights<<<dim3(6912), dim3(256), 0, stream>>>(
        w_proj, w_qkv, w_fc1, w_fc2, WPROJb, Wh, Wl, WFC1b, WFC2b);

    ln_f16x2<<<dim3(2 * BATCH * NTOK), dim3(256), 0, stream>>>(
        xin_m[0], xin_m[1], g1, b1, Xbase);

    for (int m = 0; m < 2; ++m) {
        float* corr = out + (m ? O_CT : O_CR);
        ushort_t* ATTbm = m ? ATTb1 : ATTb0;
        ushort_t* Xh = Xbase + (LL)m * 2 * SZH;
        ushort_t* Xl = Xh + SZH;

        gemm_qk<<<dim3(12, 80), dim3(256), 0, stream>>>(
            Xh, Xl, Wh, Wl, Qh2, Qm2, Kh2, Km2);

        gemm_v<<<dim3(6, 80), dim3(256), 0, stream>>>(
            Xh, Wh + (LL)1536 * 768, Vt);

        fused_attn<<<dim3(1920), dim3(256), 0, stream>>>(
            Qh2, Qm2, Kh2, Km2, Vt, corr, ATTbm, part, m);
    }

    rank_all<<<dim3(BATCH), dim3(256), 0, stream>>>(part, gis, git, js, srcmap, out);

    gemm_mfma<2><<<dim3(6, 122), dim3(256), 0, stream>>>(
        ATTb0, WPROJb, X1c, b_proj, xin_m[0], xin_m[1], srcmap,
        768, 768, 768, 768, 768);

    ln_kernel<true><<<dim3(2 * BATCH * NK), dim3(256), 0, stream>>>(
        X1c, g2, b2, XN2b);

    gemm_mfma<1><<<dim3(24, 122), dim3(256), 0, stream>>>(
        XN2b, WFC1b, H1b, b_fc1, nullptr, nullptr, nullptr, 768, 768, 768, 3072, 0);

    gemm_mfma<2><<<dim3(6, 122), dim3(256), 0, stream>>>(
        H1b, WFC2b, out + O_XRGB, b_fc2, X1c, nullptr, nullptr,
        3072, 3072, 3072, 768, 768);
}